// Round 1
// baseline (2215.685 us; speedup 1.0000x reference)
//
#include <hip/hip_runtime.h>
#include <math.h>

#define Bc 4
#define Sc 2048
#define Ec 1024
#define Hc 16
#define DHc 64

// ---------------------------------------------------------------------------
// QKV projection: out[proj][b,h,s,d] = sum_e x[b,s,e]*W[proj][h,e,d] + bias
// GEMM: M=8192 (b*s), N=3072 (proj*h*d), K=1024. BM=BN=128, BK=16.
// 256 threads, 8x8 per thread as 2x2 groups of 4x4 (halves 64 apart).
// ---------------------------------------------------------------------------
__global__ __launch_bounds__(256)
void qkv_proj_kernel(const float* __restrict__ x,
                     const float* __restrict__ Wq, const float* __restrict__ bq,
                     const float* __restrict__ Wk, const float* __restrict__ bk,
                     const float* __restrict__ Wv, const float* __restrict__ bv,
                     float* __restrict__ qo, float* __restrict__ ko, float* __restrict__ vo)
{
    __shared__ float As[16][132];   // [k][m], padded: +1 float4 keeps 16B align, breaks bank aliasing
    __shared__ float Bs[16][128];   // [k][n], row-major stores

    const int t = threadIdx.x;
    const int mBase = blockIdx.y * 128;
    const int cBase = blockIdx.x * 128;          // 0..3071
    const int proj = cBase >> 10;                // 0=q 1=k 2=v
    const float* __restrict__ W    = (proj == 0) ? Wq : (proj == 1) ? Wk : Wv;
    const float* __restrict__ bias = (proj == 0) ? bq : (proj == 1) ? bk : bv;
    float* __restrict__ out        = (proj == 0) ? qo : (proj == 1) ? ko : vo;
    const int ccBase = cBase & (Ec - 1);         // within-proj col base

    const int tm = t >> 4;   // 0..15
    const int tn = t & 15;   // 0..15

    float acc[8][8];
    #pragma unroll
    for (int i = 0; i < 8; ++i)
        #pragma unroll
        for (int j = 0; j < 8; ++j) acc[i][j] = 0.f;

    for (int k0 = 0; k0 < Ec; k0 += 16) {
        // ---- stage A tile (128 rows x 16 k), transposed into As[k][m]
        #pragma unroll
        for (int l = 0; l < 2; ++l) {
            int idx = t + l * 256;
            int row = idx >> 2, kq = idx & 3;
            float4 a = *(const float4*)(x + (size_t)(mBase + row) * Ec + k0 + kq * 4);
            As[kq * 4 + 0][row] = a.x;
            As[kq * 4 + 1][row] = a.y;
            As[kq * 4 + 2][row] = a.z;
            As[kq * 4 + 3][row] = a.w;
        }
        // ---- stage B tile (16 k x 128 cols); W[h,e,d] contiguous in d
        #pragma unroll
        for (int l = 0; l < 2; ++l) {
            int idx = t + l * 256;
            int kk = idx >> 5, f = idx & 31;
            int cc = ccBase + f * 4;             // within-proj col (float4 stays inside a head)
            int h = cc >> 6, d = cc & 63;
            float4 bfr = *(const float4*)(W + ((size_t)h * Ec + (k0 + kk)) * DHc + d);
            *(float4*)&Bs[kk][f * 4] = bfr;
        }
        __syncthreads();
        #pragma unroll
        for (int kk = 0; kk < 16; ++kk) {
            float a[8], bb[8];
            *(float4*)&a[0]  = *(const float4*)&As[kk][tm * 4];
            *(float4*)&a[4]  = *(const float4*)&As[kk][64 + tm * 4];
            *(float4*)&bb[0] = *(const float4*)&Bs[kk][tn * 4];
            *(float4*)&bb[4] = *(const float4*)&Bs[kk][64 + tn * 4];
            #pragma unroll
            for (int i = 0; i < 8; ++i)
                #pragma unroll
                for (int j = 0; j < 8; ++j)
                    acc[i][j] += a[i] * bb[j];
        }
        __syncthreads();
    }

    // ---- epilogue: add bias, scatter to [B,H,S,DH]
    #pragma unroll
    for (int ci = 0; ci < 2; ++ci) {
        int cc0 = ccBase + ci * 64 + tn * 4;     // within-proj col of first of 4
        int h = cc0 >> 6;
        int d0 = cc0 & 63;
        float4 bb4 = *(const float4*)(bias + h * DHc + d0);
        #pragma unroll
        for (int ri = 0; ri < 2; ++ri) {
            #pragma unroll
            for (int i = 0; i < 4; ++i) {
                int m = mBase + ri * 64 + tm * 4 + i;
                int b = m >> 11, s = m & (Sc - 1);
                float4 o;
                o.x = acc[ri * 4 + i][ci * 4 + 0] + bb4.x;
                o.y = acc[ri * 4 + i][ci * 4 + 1] + bb4.y;
                o.z = acc[ri * 4 + i][ci * 4 + 2] + bb4.z;
                o.w = acc[ri * 4 + i][ci * 4 + 3] + bb4.w;
                *(float4*)(out + ((size_t)(b * Hc + h) * Sc + s) * DHc + d0) = o;
            }
        }
    }
}

// ---------------------------------------------------------------------------
// Flash attention (no mask): one block per (b, h, 64-row q tile).
// K/V tiles 64x64 in LDS; online softmax; XOR-swizzled Q/K/P so the hot
// ds_read_b128 patterns are conflict-free. LDS = 4*16KB = 64KB.
// Thread (tr,tc): S rows {tr+16i}, S cols {tc+16j}; O cols {tc*4+j}.
// ---------------------------------------------------------------------------
__global__ __launch_bounds__(256)
void attn_kernel(const float* __restrict__ q, const float* __restrict__ k,
                 const float* __restrict__ v, float* __restrict__ concat)
{
    __shared__ float Qs[64][64];   // swizzled: float4 f at slot f^(row&15)
    __shared__ float Ks[64][64];   // swizzled same
    __shared__ float Vs[64][64];   // linear
    __shared__ float Ps[64][64];   // swizzled: group g at slot g^(row&15)

    const int t = threadIdx.x;
    const int tr = t >> 4;          // 0..15
    const int tc = t & 15;          // 0..15
    const int qt = blockIdx.x, h = blockIdx.y, b = blockIdx.z;

    const float* qp = q + ((size_t)(b * Hc + h) * Sc + qt * 64) * DHc;
    const float* kp = k + (size_t)(b * Hc + h) * Sc * DHc;
    const float* vp = v + (size_t)(b * Hc + h) * Sc * DHc;

    // load Q tile once, scale by 1/sqrt(DH), swizzle
    #pragma unroll
    for (int l = 0; l < 4; ++l) {
        int idx = t + l * 256;
        int row = idx >> 4, f = idx & 15;
        float4 a = *(const float4*)(qp + row * DHc + f * 4);
        a.x *= 0.125f; a.y *= 0.125f; a.z *= 0.125f; a.w *= 0.125f;
        *(float4*)&Qs[row][(f ^ (row & 15)) * 4] = a;
    }

    float o[4][4];
    float m_i[4], l_i[4];
    #pragma unroll
    for (int i = 0; i < 4; ++i) {
        m_i[i] = -1e30f; l_i[i] = 0.f;
        #pragma unroll
        for (int j = 0; j < 4; ++j) o[i][j] = 0.f;
    }

    for (int kt = 0; kt < Sc / 64; ++kt) {
        __syncthreads();           // prev iter's PV readers done before overwrite
        #pragma unroll
        for (int l = 0; l < 4; ++l) {
            int idx = t + l * 256;
            int row = idx >> 4, f = idx & 15;
            const float* kt_p = kp + (size_t)kt * 64 * DHc + row * DHc + f * 4;
            const float* vt_p = vp + (size_t)kt * 64 * DHc + row * DHc + f * 4;
            float4 kk4 = *(const float4*)kt_p;
            float4 vv4 = *(const float4*)vt_p;
            *(float4*)&Ks[row][(f ^ (row & 15)) * 4] = kk4;
            *(float4*)&Vs[row][f * 4] = vv4;
        }
        __syncthreads();

        // ---- S = Q K^T (scaled): 4x4 per thread
        float s[4][4];
        #pragma unroll
        for (int i = 0; i < 4; ++i)
            #pragma unroll
            for (int j = 0; j < 4; ++j) s[i][j] = 0.f;

        #pragma unroll
        for (int e4 = 0; e4 < 16; ++e4) {
            float qv[4][4], kv[4][4];
            int qs = (e4 ^ tr) * 4;
            int ks = (e4 ^ tc) * 4;
            #pragma unroll
            for (int i = 0; i < 4; ++i)
                *(float4*)qv[i] = *(const float4*)&Qs[tr + 16 * i][qs];
            #pragma unroll
            for (int j = 0; j < 4; ++j)
                *(float4*)kv[j] = *(const float4*)&Ks[tc + 16 * j][ks];
            #pragma unroll
            for (int i = 0; i < 4; ++i)
                #pragma unroll
                for (int j = 0; j < 4; ++j)
                    #pragma unroll
                    for (int e = 0; e < 4; ++e)
                        s[i][j] += qv[i][e] * kv[j][e];
        }

        // ---- online softmax (rows shared by 16 lanes tc)
        float p[4][4];
        #pragma unroll
        for (int i = 0; i < 4; ++i) {
            float mx = fmaxf(fmaxf(s[i][0], s[i][1]), fmaxf(s[i][2], s[i][3]));
            mx = fmaxf(mx, __shfl_xor(mx, 1));
            mx = fmaxf(mx, __shfl_xor(mx, 2));
            mx = fmaxf(mx, __shfl_xor(mx, 4));
            mx = fmaxf(mx, __shfl_xor(mx, 8));
            float mn = fmaxf(m_i[i], mx);
            float ef = __expf(m_i[i] - mn);
            float ps = 0.f;
            #pragma unroll
            for (int j = 0; j < 4; ++j) {
                p[i][j] = __expf(s[i][j] - mn);
                ps += p[i][j];
            }
            ps += __shfl_xor(ps, 1);
            ps += __shfl_xor(ps, 2);
            ps += __shfl_xor(ps, 4);
            ps += __shfl_xor(ps, 8);
            l_i[i] = l_i[i] * ef + ps;
            m_i[i] = mn;
            #pragma unroll
            for (int j = 0; j < 4; ++j) o[i][j] *= ef;
        }

        __syncthreads();
        // ---- store P (swizzled by float4 group)
        #pragma unroll
        for (int i = 0; i < 4; ++i)
            #pragma unroll
            for (int j = 0; j < 4; ++j) {
                int R = tr + 16 * i, C = tc + 16 * j;
                Ps[R][((((C >> 2) ^ tr) << 2) | (C & 3))] = p[i][j];
            }
        __syncthreads();

        // ---- O += P V : per thread rows {tr+16i}, out cols {tc*4+j}
        #pragma unroll
        for (int t4 = 0; t4 < 16; ++t4) {
            float pa[4][4];
            #pragma unroll
            for (int i = 0; i < 4; ++i)
                *(float4*)pa[i] = *(const float4*)&Ps[tr + 16 * i][(t4 ^ tr) * 4];
            #pragma unroll
            for (int u = 0; u < 4; ++u) {
                float vv[4];
                *(float4*)vv = *(const float4*)&Vs[t4 * 4 + u][tc * 4];
                #pragma unroll
                for (int i = 0; i < 4; ++i)
                    #pragma unroll
                    for (int j = 0; j < 4; ++j)
                        o[i][j] += pa[i][u] * vv[j];
            }
        }
    }

    // ---- finalize: divide by l, write concat[b, s, h*64 + d]
    #pragma unroll
    for (int i = 0; i < 4; ++i) {
        float inv = 1.f / l_i[i];
        int srow = qt * 64 + tr + 16 * i;
        float4 ov;
        ov.x = o[i][0] * inv;
        ov.y = o[i][1] * inv;
        ov.z = o[i][2] * inv;
        ov.w = o[i][3] * inv;
        *(float4*)(concat + ((size_t)b * Sc + srow) * Ec + h * DHc + tc * 4) = ov;
    }
}

// ---------------------------------------------------------------------------
// Output projection: out[m,e] = sum_f concat[m,f] * Wo[e,f] + bo[e]
// Same GEMM structure; Wo accessed transposed (contiguous in k).
// ---------------------------------------------------------------------------
__global__ __launch_bounds__(256)
void out_proj_kernel(const float* __restrict__ concat, const float* __restrict__ Wo,
                     const float* __restrict__ bo, float* __restrict__ out)
{
    __shared__ float As[16][132];
    __shared__ float Bs[16][132];

    const int t = threadIdx.x;
    const int mBase = blockIdx.y * 128;
    const int nBase = blockIdx.x * 128;
    const int tm = t >> 4;
    const int tn = t & 15;

    float acc[8][8];
    #pragma unroll
    for (int i = 0; i < 8; ++i)
        #pragma unroll
        for (int j = 0; j < 8; ++j) acc[i][j] = 0.f;

    for (int k0 = 0; k0 < Ec; k0 += 16) {
        #pragma unroll
        for (int l = 0; l < 2; ++l) {
            int idx = t + l * 256;
            int row = idx >> 2, kq = idx & 3;
            float4 a = *(const float4*)(concat + (size_t)(mBase + row) * Ec + k0 + kq * 4);
            As[kq * 4 + 0][row] = a.x;
            As[kq * 4 + 1][row] = a.y;
            As[kq * 4 + 2][row] = a.z;
            As[kq * 4 + 3][row] = a.w;
        }
        #pragma unroll
        for (int l = 0; l < 2; ++l) {
            int idx = t + l * 256;
            int n = idx >> 2, kq = idx & 3;
            float4 w = *(const float4*)(Wo + (size_t)(nBase + n) * Ec + k0 + kq * 4);
            Bs[kq * 4 + 0][n] = w.x;
            Bs[kq * 4 + 1][n] = w.y;
            Bs[kq * 4 + 2][n] = w.z;
            Bs[kq * 4 + 3][n] = w.w;
        }
        __syncthreads();
        #pragma unroll
        for (int kk = 0; kk < 16; ++kk) {
            float a[8], bb[8];
            *(float4*)&a[0]  = *(const float4*)&As[kk][tm * 4];
            *(float4*)&a[4]  = *(const float4*)&As[kk][64 + tm * 4];
            *(float4*)&bb[0] = *(const float4*)&Bs[kk][tn * 4];
            *(float4*)&bb[4] = *(const float4*)&Bs[kk][64 + tn * 4];
            #pragma unroll
            for (int i = 0; i < 8; ++i)
                #pragma unroll
                for (int j = 0; j < 8; ++j)
                    acc[i][j] += a[i] * bb[j];
        }
        __syncthreads();
    }

    #pragma unroll
    for (int ci = 0; ci < 2; ++ci) {
        int col0 = nBase + ci * 64 + tn * 4;
        float4 bb4 = *(const float4*)(bo + col0);
        #pragma unroll
        for (int ri = 0; ri < 2; ++ri) {
            #pragma unroll
            for (int i = 0; i < 4; ++i) {
                int m = mBase + ri * 64 + tm * 4 + i;
                float4 ov;
                ov.x = acc[ri * 4 + i][ci * 4 + 0] + bb4.x;
                ov.y = acc[ri * 4 + i][ci * 4 + 1] + bb4.y;
                ov.z = acc[ri * 4 + i][ci * 4 + 2] + bb4.z;
                ov.w = acc[ri * 4 + i][ci * 4 + 3] + bb4.w;
                *(float4*)(out + (size_t)m * Ec + col0) = ov;
            }
        }
    }
}

// ---------------------------------------------------------------------------
extern "C" void kernel_launch(void* const* d_in, const int* in_sizes, int n_in,
                              void* d_out, int out_size, void* d_ws, size_t ws_size,
                              hipStream_t stream)
{
    const float* x  = (const float*)d_in[0];
    const float* Wq = (const float*)d_in[1];
    const float* bq = (const float*)d_in[2];
    const float* Wk = (const float*)d_in[3];
    const float* bk = (const float*)d_in[4];
    const float* Wv = (const float*)d_in[5];
    const float* bv = (const float*)d_in[6];
    const float* Wo = (const float*)d_in[7];
    const float* bo = (const float*)d_in[8];
    float* out = (float*)d_out;

    // workspace layout: q | k | v | concat, each B*H*S*DH = 8M floats (32 MB)
    const size_t per = (size_t)Bc * Hc * Sc * DHc;   // 8388608
    float* ws = (float*)d_ws;
    float* q      = ws;
    float* k      = ws + per;
    float* v      = ws + 2 * per;
    float* concat = ws + 3 * per;

    dim3 g1(3 * Ec / 128, (Bc * Sc) / 128);   // (24, 64)
    qkv_proj_kernel<<<g1, 256, 0, stream>>>(x, Wq, bq, Wk, bk, Wv, bv, q, k, v);

    dim3 g2(Sc / 64, Hc, Bc);                 // (32, 16, 4)
    attn_kernel<<<g2, 256, 0, stream>>>(q, k, v, concat);

    dim3 g3(Ec / 128, (Bc * Sc) / 128);       // (8, 64)
    out_proj_kernel<<<g3, 256, 0, stream>>>(concat, Wo, bo, out);
}

// Round 2
// 347.593 us; speedup vs baseline: 6.3744x; 6.3744x over previous
//
#include <hip/hip_runtime.h>
#include <math.h>

#define Bc 4
#define Sc 2048
#define Ec 1024
#define Hc 16
#define DHc 64

typedef unsigned short u16;
typedef __attribute__((ext_vector_type(8))) short short8;   // 8 bf16 = 4 VGPR
typedef __attribute__((ext_vector_type(4))) float f32x4;
typedef __attribute__((ext_vector_type(2))) unsigned short u16x2;

__device__ __forceinline__ u16 f2bf(float f) {
    unsigned int u = __float_as_uint(f);
    u += 0x7FFFu + ((u >> 16) & 1u);          // round-to-nearest-even
    return (u16)(u >> 16);
}

// global -> LDS direct copy, 16B per lane. LDS dest is wave-uniform base
// (+ lane*16 implicit); global src is per-lane.
__device__ __forceinline__ void gl_lds16(const void* g, void* l) {
    __builtin_amdgcn_global_load_lds(
        (const __attribute__((address_space(1))) unsigned int*)g,
        (__attribute__((address_space(3))) unsigned int*)l,
        16, 0, 0);
}

// ---------------------------------------------------------------------------
// cast fp32 -> bf16, 8 elems/thread
// ---------------------------------------------------------------------------
__global__ __launch_bounds__(256)
void cast_bf16_kernel(const float* __restrict__ in, u16* __restrict__ out, int n8)
{
    int i = blockIdx.x * 256 + threadIdx.x;
    if (i >= n8) return;
    const float* p = in + (size_t)i * 8;
    float4 a = *(const float4*)p;
    float4 b = *(const float4*)(p + 4);
    short8 v;
    v[0] = (short)f2bf(a.x); v[1] = (short)f2bf(a.y);
    v[2] = (short)f2bf(a.z); v[3] = (short)f2bf(a.w);
    v[4] = (short)f2bf(b.x); v[5] = (short)f2bf(b.y);
    v[6] = (short)f2bf(b.z); v[7] = (short)f2bf(b.w);
    *(short8*)(out + (size_t)i * 8) = v;
}

// ---------------------------------------------------------------------------
// transpose+cast W[proj][h][e][d] fp32 -> Wtb[(proj*16+h)*64+d][e] bf16
// one 64(e) x 64(d) tile per block
// ---------------------------------------------------------------------------
__global__ __launch_bounds__(256)
void transW_kernel(const float* __restrict__ Wq, const float* __restrict__ Wk,
                   const float* __restrict__ Wv, u16* __restrict__ Wtb)
{
    __shared__ float T[64][65];
    const int t = threadIdx.x;
    const int e0 = blockIdx.x * 64;
    const int h = blockIdx.y;
    const int proj = blockIdx.z;
    const float* W = (proj == 0) ? Wq : (proj == 1) ? Wk : Wv;

    #pragma unroll
    for (int i = 0; i < 4; ++i) {
        int fid = t + i * 256;
        int row = fid >> 4, c4 = fid & 15;
        float4 v = *(const float4*)(W + ((size_t)h * Ec + e0 + row) * DHc + c4 * 4);
        T[row][c4 * 4 + 0] = v.x; T[row][c4 * 4 + 1] = v.y;
        T[row][c4 * 4 + 2] = v.z; T[row][c4 * 4 + 3] = v.w;
    }
    __syncthreads();
    const int d = t >> 2, ech = (t & 3) * 16;
    u16* dst = Wtb + ((size_t)(proj * Hc + h) * DHc + d) * Ec + e0 + ech;
    #pragma unroll
    for (int j = 0; j < 16; j += 2) {
        u16x2 v2;
        v2.x = f2bf(T[ech + j][d]);
        v2.y = f2bf(T[ech + j + 1][d]);
        *(u16x2*)(dst + j) = v2;
    }
}

// ---------------------------------------------------------------------------
// QKV projection GEMM (bf16 MFMA): M=8192, N=3072, K=1024.
// BM=BN=128, BK=64, 4 waves (2x2), 4x4 16x16 frags per wave.
// LDS slots (16B) XOR-swizzled: slot' = g ^ (row&7); staged via pre-swizzled
// global source so global_load_lds dest stays linear.
// Outputs: qb [bh][s][d] (pre-scaled 1/8), kb [bh][s][d], vb [bh][d][s] - all bf16.
// ---------------------------------------------------------------------------
__global__ __launch_bounds__(256)
void qkv_mfma_kernel(const u16* __restrict__ xb, const u16* __restrict__ Wtb,
                     const float* __restrict__ bq, const float* __restrict__ bk,
                     const float* __restrict__ bv,
                     u16* __restrict__ qb, u16* __restrict__ kb, u16* __restrict__ vb)
{
    __shared__ __align__(16) u16 As[128 * 64];
    __shared__ __align__(16) u16 Bs[128 * 64];

    const int t = threadIdx.x;
    const int w = t >> 6, l = t & 63;
    const int wr = w >> 1, wc = w & 1;
    const int mBase = blockIdx.y * 128;
    const int nBase = blockIdx.x * 128;
    const int proj = nBase >> 10;            // block never straddles a proj
    const int nIn = nBase & (Ec - 1);
    const int lr = l >> 3, ls = l & 7;
    const int lq = l >> 4, ln = l & 15;

    f32x4 acc[4][4];
    #pragma unroll
    for (int i = 0; i < 4; ++i)
        #pragma unroll
        for (int j = 0; j < 4; ++j) acc[i][j] = (f32x4)0.f;

    for (int k0 = 0; k0 < Ec; k0 += 64) {
        __syncthreads();                     // prior compute done before overwrite
        #pragma unroll
        for (int c = 0; c < 8; ++c) {
            int cg = w * 8 + c;
            if (cg < 16) {                   // A rows
                int row = cg * 8 + lr;
                int g = ls ^ (row & 7);
                gl_lds16(xb + ((size_t)(mBase + row)) * Ec + k0 + g * 8,
                         (void*)(As + cg * 512));
            } else {                         // B cols (Wtb rows)
                int col = (cg - 16) * 8 + lr;
                int g = ls ^ (col & 7);
                gl_lds16(Wtb + ((size_t)proj * Ec + nIn + col) * Ec + k0 + g * 8,
                         (void*)(Bs + (cg - 16) * 512));
            }
        }
        __syncthreads();                     // drains vmcnt -> tiles ready

        #pragma unroll
        for (int ks = 0; ks < 2; ++ks) {
            short8 af[4], bfr[4];
            int gg = ks * 4 + lq;
            #pragma unroll
            for (int fm = 0; fm < 4; ++fm) {
                int row = wr * 64 + fm * 16 + ln;
                af[fm] = *(const short8*)(As + row * 64 + ((gg ^ (row & 7)) * 8));
            }
            #pragma unroll
            for (int fn = 0; fn < 4; ++fn) {
                int col = wc * 64 + fn * 16 + ln;
                bfr[fn] = *(const short8*)(Bs + col * 64 + ((gg ^ (col & 7)) * 8));
            }
            #pragma unroll
            for (int fm = 0; fm < 4; ++fm)
                #pragma unroll
                for (int fn = 0; fn < 4; ++fn)
                    acc[fm][fn] = __builtin_amdgcn_mfma_f32_16x16x32_bf16(
                        af[fm], bfr[fn], acc[fm][fn], 0, 0, 0);
        }
    }

    // epilogue: bias, downcast, scatter (Q scaled 1/8; V transposed [d][s])
    const float* bias = (proj == 0) ? bq : (proj == 1) ? bk : bv;
    #pragma unroll
    for (int fn = 0; fn < 4; ++fn) {
        int n = nBase + wc * 64 + fn * 16 + ln;
        int cc = n & (Ec - 1);
        int hh = cc >> 6, d = cc & 63;
        float bv_ = bias[cc];
        #pragma unroll
        for (int fm = 0; fm < 4; ++fm) {
            #pragma unroll
            for (int r = 0; r < 4; ++r) {
                int m = mBase + wr * 64 + fm * 16 + lq * 4 + r;
                int b = m >> 11, s = m & (Sc - 1);
                int bh = b * Hc + hh;
                float vv = acc[fm][fn][r] + bv_;
                if (proj == 0)      qb[((size_t)bh * Sc + s) * DHc + d] = f2bf(vv * 0.125f);
                else if (proj == 1) kb[((size_t)bh * Sc + s) * DHc + d] = f2bf(vv);
                else                vb[((size_t)bh * DHc + d) * Sc + s] = f2bf(vv);
            }
        }
    }
}

// ---------------------------------------------------------------------------
// Flash attention, bf16 MFMA. Block = (qtile 64, h, b), 4 waves; wave w owns
// q-rows [qt*64+w*16, +16). K staged [key][e], V staged [d][key] (already
// transposed in memory), both slot-swizzled. P round-trips through per-wave
// swizzled LDS to become the PV A-operand.
// ---------------------------------------------------------------------------
__global__ __launch_bounds__(256)
void attn_mfma_kernel(const u16* __restrict__ qb, const u16* __restrict__ kb,
                      const u16* __restrict__ vb, u16* __restrict__ concatb)
{
    __shared__ __align__(16) u16 Kt[64 * 64];
    __shared__ __align__(16) u16 Vt[64 * 64];
    __shared__ __align__(16) u16 Ps[4 * 16 * 64];

    const int t = threadIdx.x;
    const int w = t >> 6, l = t & 63;
    const int qt = blockIdx.x, h = blockIdx.y, b = blockIdx.z;
    const int bh = b * Hc + h;
    const u16* qp = qb + ((size_t)bh * Sc + qt * 64 + w * 16) * DHc;
    const u16* kp = kb + (size_t)bh * Sc * DHc;
    const u16* vp = vb + (size_t)bh * DHc * Sc;

    const int lq = l >> 4, ln = l & 15;
    const int lr = l >> 3, ls = l & 7;

    // Q fragments live in registers for the whole kernel (Q pre-scaled by 1/8)
    short8 qf[2];
    qf[0] = *(const short8*)(qp + ln * DHc + lq * 8);
    qf[1] = *(const short8*)(qp + ln * DHc + 32 + lq * 8);

    f32x4 o[4];
    #pragma unroll
    for (int i = 0; i < 4; ++i) o[i] = (f32x4)0.f;
    float m_i[4], l_i[4];
    #pragma unroll
    for (int r = 0; r < 4; ++r) { m_i[r] = -1e30f; l_i[r] = 0.f; }

    for (int kt = 0; kt < Sc / 64; ++kt) {
        __syncthreads();                     // all waves done reading prev tiles
        #pragma unroll
        for (int c = 0; c < 4; ++c) {
            int cg = w * 4 + c;
            if (cg < 8) {                    // K rows
                int row = cg * 8 + lr;
                int g = ls ^ (row & 7);
                gl_lds16(kp + ((size_t)(kt * 64 + row)) * DHc + g * 8,
                         (void*)(Kt + cg * 512));
            } else {                         // V^T rows (d)
                int d = (cg - 8) * 8 + lr;
                int g = ls ^ (d & 7);
                gl_lds16(vp + (size_t)d * Sc + kt * 64 + g * 8,
                         (void*)(Vt + (cg - 8) * 512));
            }
        }
        __syncthreads();

        // ---- S = Q K^T  (D rows = q = lq*4+r, cols = key = fn*16+ln)
        f32x4 s[4];
        #pragma unroll
        for (int fn = 0; fn < 4; ++fn) s[fn] = (f32x4)0.f;
        #pragma unroll
        for (int ks = 0; ks < 2; ++ks) {
            int gg = ks * 4 + lq;
            #pragma unroll
            for (int fn = 0; fn < 4; ++fn) {
                int key = fn * 16 + ln;
                short8 kf = *(const short8*)(Kt + key * 64 + ((gg ^ (key & 7)) * 8));
                s[fn] = __builtin_amdgcn_mfma_f32_16x16x32_bf16(qf[ks], kf, s[fn], 0, 0, 0);
            }
        }

        // ---- online softmax over 64 keys (row shared by 16 contiguous lanes)
        float p[4][4];                       // [fn][r]
        #pragma unroll
        for (int r = 0; r < 4; ++r) {
            float mx = fmaxf(fmaxf(s[0][r], s[1][r]), fmaxf(s[2][r], s[3][r]));
            mx = fmaxf(mx, __shfl_xor(mx, 1));
            mx = fmaxf(mx, __shfl_xor(mx, 2));
            mx = fmaxf(mx, __shfl_xor(mx, 4));
            mx = fmaxf(mx, __shfl_xor(mx, 8));
            float nm = fmaxf(m_i[r], mx);
            float ef = __expf(m_i[r] - nm);
            m_i[r] = nm;
            float sum = 0.f;
            #pragma unroll
            for (int fn = 0; fn < 4; ++fn) {
                p[fn][r] = __expf(s[fn][r] - nm);
                sum += p[fn][r];
            }
            sum += __shfl_xor(sum, 1);
            sum += __shfl_xor(sum, 2);
            sum += __shfl_xor(sum, 4);
            sum += __shfl_xor(sum, 8);
            l_i[r] = l_i[r] * ef + sum;
            #pragma unroll
            for (int fd = 0; fd < 4; ++fd) o[fd][r] *= ef;
        }

        // ---- P -> per-wave LDS (swizzled), then reread as PV A-operand
        u16* pw = Ps + w * 1024;
        #pragma unroll
        for (int fn = 0; fn < 4; ++fn) {
            int col = fn * 16 + ln;
            int g = col >> 3, co = col & 7;
            #pragma unroll
            for (int r = 0; r < 4; ++r) {
                int row = lq * 4 + r;
                pw[row * 64 + ((g ^ (row & 7)) * 8) + co] = f2bf(p[fn][r]);
            }
        }
        asm volatile("s_waitcnt lgkmcnt(0)" ::: "memory");

        // ---- O += P V   (A = P [q][key], B = V [key][d] via Vt[d][key])
        #pragma unroll
        for (int ks = 0; ks < 2; ++ks) {
            int gg = ks * 4 + lq;
            short8 pf = *(const short8*)(pw + ln * 64 + ((gg ^ (ln & 7)) * 8));
            #pragma unroll
            for (int fd = 0; fd < 4; ++fd) {
                int d = fd * 16 + ln;
                short8 vf = *(const short8*)(Vt + d * 64 + ((gg ^ (d & 7)) * 8));
                o[fd] = __builtin_amdgcn_mfma_f32_16x16x32_bf16(pf, vf, o[fd], 0, 0, 0);
            }
        }
    }

    // ---- epilogue: normalize, downcast, write concat [b][s][h*64+d] bf16
    #pragma unroll
    for (int r = 0; r < 4; ++r) {
        float inv = 1.f / l_i[r];
        int q = qt * 64 + w * 16 + lq * 4 + r;
        #pragma unroll
        for (int fd = 0; fd < 4; ++fd) {
            int d = h * DHc + fd * 16 + ln;
            concatb[((size_t)b * Sc + q) * Ec + d] = f2bf(o[fd][r] * inv);
        }
    }
}

// ---------------------------------------------------------------------------
// Output projection GEMM (bf16 MFMA): out[m][n] = concat[m][:] . Wo[n][:] + bo
// Wo bf16 is already [n][k] row-major. fp32 output.
// ---------------------------------------------------------------------------
__global__ __launch_bounds__(256)
void oproj_mfma_kernel(const u16* __restrict__ cb, const u16* __restrict__ Wob,
                       const float* __restrict__ bo, float* __restrict__ out)
{
    __shared__ __align__(16) u16 As[128 * 64];
    __shared__ __align__(16) u16 Bs[128 * 64];

    const int t = threadIdx.x;
    const int w = t >> 6, l = t & 63;
    const int wr = w >> 1, wc = w & 1;
    const int mBase = blockIdx.y * 128;
    const int nBase = blockIdx.x * 128;
    const int lr = l >> 3, ls = l & 7;
    const int lq = l >> 4, ln = l & 15;

    f32x4 acc[4][4];
    #pragma unroll
    for (int i = 0; i < 4; ++i)
        #pragma unroll
        for (int j = 0; j < 4; ++j) acc[i][j] = (f32x4)0.f;

    for (int k0 = 0; k0 < Ec; k0 += 64) {
        __syncthreads();
        #pragma unroll
        for (int c = 0; c < 8; ++c) {
            int cg = w * 8 + c;
            if (cg < 16) {
                int row = cg * 8 + lr;
                int g = ls ^ (row & 7);
                gl_lds16(cb + ((size_t)(mBase + row)) * Ec + k0 + g * 8,
                         (void*)(As + cg * 512));
            } else {
                int col = (cg - 16) * 8 + lr;
                int g = ls ^ (col & 7);
                gl_lds16(Wob + ((size_t)(nBase + col)) * Ec + k0 + g * 8,
                         (void*)(Bs + (cg - 16) * 512));
            }
        }
        __syncthreads();

        #pragma unroll
        for (int ks = 0; ks < 2; ++ks) {
            short8 af[4], bfr[4];
            int gg = ks * 4 + lq;
            #pragma unroll
            for (int fm = 0; fm < 4; ++fm) {
                int row = wr * 64 + fm * 16 + ln;
                af[fm] = *(const short8*)(As + row * 64 + ((gg ^ (row & 7)) * 8));
            }
            #pragma unroll
            for (int fn = 0; fn < 4; ++fn) {
                int col = wc * 64 + fn * 16 + ln;
                bfr[fn] = *(const short8*)(Bs + col * 64 + ((gg ^ (col & 7)) * 8));
            }
            #pragma unroll
            for (int fm = 0; fm < 4; ++fm)
                #pragma unroll
                for (int fn = 0; fn < 4; ++fn)
                    acc[fm][fn] = __builtin_amdgcn_mfma_f32_16x16x32_bf16(
                        af[fm], bfr[fn], acc[fm][fn], 0, 0, 0);
        }
    }

    #pragma unroll
    for (int fn = 0; fn < 4; ++fn) {
        int n = nBase + wc * 64 + fn * 16 + ln;
        float bb = bo[n];
        #pragma unroll
        for (int fm = 0; fm < 4; ++fm) {
            #pragma unroll
            for (int r = 0; r < 4; ++r) {
                int m = mBase + wr * 64 + fm * 16 + lq * 4 + r;
                out[(size_t)m * Ec + n] = acc[fm][fn][r] + bb;
            }
        }
    }
}

// ---------------------------------------------------------------------------
extern "C" void kernel_launch(void* const* d_in, const int* in_sizes, int n_in,
                              void* d_out, int out_size, void* d_ws, size_t ws_size,
                              hipStream_t stream)
{
    const float* x  = (const float*)d_in[0];
    const float* Wq = (const float*)d_in[1];
    const float* bq = (const float*)d_in[2];
    const float* Wk = (const float*)d_in[3];
    const float* bk = (const float*)d_in[4];
    const float* Wv = (const float*)d_in[5];
    const float* bv = (const float*)d_in[6];
    const float* Wo = (const float*)d_in[7];
    const float* bo = (const float*)d_in[8];
    float* out = (float*)d_out;

    char* ws = (char*)d_ws;
    u16* xb   = (u16*)(ws);                   // 16 MB  [8192][1024]
    u16* Wtb  = (u16*)(ws + (16u << 20));     //  6 MB  [3*1024][1024]
    u16* Wob  = (u16*)(ws + (22u << 20));     //  2 MB  [1024][1024]
    u16* qbuf = (u16*)(ws + (24u << 20));     // 16 MB  [bh][s][d], pre-scaled
    u16* kbuf = (u16*)(ws + (40u << 20));     // 16 MB  [bh][s][d]
    u16* vbuf = (u16*)(ws + (56u << 20));     // 16 MB  [bh][d][s]  (transposed)
    u16* cbuf = (u16*)(ws + (72u << 20));     // 16 MB  [b][s][e]

    // prep: casts + weight transpose
    cast_bf16_kernel<<<(Bc * Sc * Ec / 8 + 255) / 256, 256, 0, stream>>>(x, xb, Bc * Sc * Ec / 8);
    cast_bf16_kernel<<<(Ec * Ec / 8 + 255) / 256, 256, 0, stream>>>(Wo, Wob, Ec * Ec / 8);
    dim3 gt(Ec / 64, Hc, 3);
    transW_kernel<<<gt, 256, 0, stream>>>(Wq, Wk, Wv, Wtb);

    dim3 g1(3 * Ec / 128, (Bc * Sc) / 128);   // (24, 64)
    qkv_mfma_kernel<<<g1, 256, 0, stream>>>(xb, Wtb, bq, bk, bv, qbuf, kbuf, vbuf);

    dim3 g2(Sc / 64, Hc, Bc);                 // (32, 16, 4)
    attn_mfma_kernel<<<g2, 256, 0, stream>>>(qbuf, kbuf, vbuf, cbuf);

    dim3 g3(Ec / 128, (Bc * Sc) / 128);       // (8, 64)
    oproj_mfma_kernel<<<g3, 256, 0, stream>>>(cbuf, Wob, bo, out);
}

// Round 3
// 289.028 us; speedup vs baseline: 7.6660x; 1.2026x over previous
//
#include <hip/hip_runtime.h>
#include <math.h>

#define Bc 4
#define Sc 2048
#define Ec 1024
#define Hc 16
#define DHc 64

typedef unsigned short u16;
typedef __attribute__((ext_vector_type(8))) short short8;   // 8 bf16 = 4 VGPR
typedef __attribute__((ext_vector_type(4))) float f32x4;
typedef __attribute__((ext_vector_type(2))) unsigned short u16x2;

__device__ __forceinline__ u16 f2bf(float f) {
    unsigned int u = __float_as_uint(f);
    u += 0x7FFFu + ((u >> 16) & 1u);          // round-to-nearest-even
    return (u16)(u >> 16);
}

// global -> LDS direct copy, 16B per lane. LDS dest is wave-uniform base
// (+ lane*16 implicit); global src is per-lane.
__device__ __forceinline__ void gl_lds16(const void* g, void* l) {
    __builtin_amdgcn_global_load_lds(
        (const __attribute__((address_space(1))) unsigned int*)g,
        (__attribute__((address_space(3))) unsigned int*)l,
        16, 0, 0);
}

// ---------------------------------------------------------------------------
// cast fp32 -> bf16, 8 elems/thread
// ---------------------------------------------------------------------------
__global__ __launch_bounds__(256)
void cast_bf16_kernel(const float* __restrict__ in, u16* __restrict__ out, int n8)
{
    int i = blockIdx.x * 256 + threadIdx.x;
    if (i >= n8) return;
    const float* p = in + (size_t)i * 8;
    float4 a = *(const float4*)p;
    float4 b = *(const float4*)(p + 4);
    short8 v;
    v[0] = (short)f2bf(a.x); v[1] = (short)f2bf(a.y);
    v[2] = (short)f2bf(a.z); v[3] = (short)f2bf(a.w);
    v[4] = (short)f2bf(b.x); v[5] = (short)f2bf(b.y);
    v[6] = (short)f2bf(b.z); v[7] = (short)f2bf(b.w);
    *(short8*)(out + (size_t)i * 8) = v;
}

// ---------------------------------------------------------------------------
// transpose+cast W[proj][h][e][d] fp32 -> Wtb[(proj*16+h)*64+d][e] bf16
// ---------------------------------------------------------------------------
__global__ __launch_bounds__(256)
void transW_kernel(const float* __restrict__ Wq, const float* __restrict__ Wk,
                   const float* __restrict__ Wv, u16* __restrict__ Wtb)
{
    __shared__ float T[64][65];
    const int t = threadIdx.x;
    const int e0 = blockIdx.x * 64;
    const int h = blockIdx.y;
    const int proj = blockIdx.z;
    const float* W = (proj == 0) ? Wq : (proj == 1) ? Wk : Wv;

    #pragma unroll
    for (int i = 0; i < 4; ++i) {
        int fid = t + i * 256;
        int row = fid >> 4, c4 = fid & 15;
        float4 v = *(const float4*)(W + ((size_t)h * Ec + e0 + row) * DHc + c4 * 4);
        T[row][c4 * 4 + 0] = v.x; T[row][c4 * 4 + 1] = v.y;
        T[row][c4 * 4 + 2] = v.z; T[row][c4 * 4 + 3] = v.w;
    }
    __syncthreads();
    const int d = t >> 2, ech = (t & 3) * 16;
    u16* dst = Wtb + ((size_t)(proj * Hc + h) * DHc + d) * Ec + e0 + ech;
    #pragma unroll
    for (int j = 0; j < 16; j += 2) {
        u16x2 v2;
        v2.x = f2bf(T[ech + j][d]);
        v2.y = f2bf(T[ech + j + 1][d]);
        *(u16x2*)(dst + j) = v2;
    }
}

// ---------------------------------------------------------------------------
// QKV projection GEMM (bf16 MFMA): M=8192, N=3072, K=1024.
// Q output pre-scaled by log2(e)/sqrt(DH) so attn softmax runs in exp2 domain.
// ---------------------------------------------------------------------------
__global__ __launch_bounds__(256)
void qkv_mfma_kernel(const u16* __restrict__ xb, const u16* __restrict__ Wtb,
                     const float* __restrict__ bq, const float* __restrict__ bk,
                     const float* __restrict__ bv,
                     u16* __restrict__ qb, u16* __restrict__ kb, u16* __restrict__ vb)
{
    __shared__ __align__(16) u16 As[128 * 64];
    __shared__ __align__(16) u16 Bs[128 * 64];

    const int t = threadIdx.x;
    const int w = t >> 6, l = t & 63;
    const int wr = w >> 1, wc = w & 1;
    const int mBase = blockIdx.y * 128;
    const int nBase = blockIdx.x * 128;
    const int proj = nBase >> 10;            // block never straddles a proj
    const int nIn = nBase & (Ec - 1);
    const int lr = l >> 3, ls = l & 7;
    const int lq = l >> 4, ln = l & 15;

    f32x4 acc[4][4];
    #pragma unroll
    for (int i = 0; i < 4; ++i)
        #pragma unroll
        for (int j = 0; j < 4; ++j) acc[i][j] = (f32x4)0.f;

    for (int k0 = 0; k0 < Ec; k0 += 64) {
        __syncthreads();
        #pragma unroll
        for (int c = 0; c < 8; ++c) {
            int cg = w * 8 + c;
            if (cg < 16) {                   // A rows
                int row = cg * 8 + lr;
                int g = ls ^ (row & 7);
                gl_lds16(xb + ((size_t)(mBase + row)) * Ec + k0 + g * 8,
                         (void*)(As + cg * 512));
            } else {                         // B cols (Wtb rows)
                int col = (cg - 16) * 8 + lr;
                int g = ls ^ (col & 7);
                gl_lds16(Wtb + ((size_t)proj * Ec + nIn + col) * Ec + k0 + g * 8,
                         (void*)(Bs + (cg - 16) * 512));
            }
        }
        __syncthreads();

        #pragma unroll
        for (int ks = 0; ks < 2; ++ks) {
            short8 af[4], bfr[4];
            int gg = ks * 4 + lq;
            #pragma unroll
            for (int fm = 0; fm < 4; ++fm) {
                int row = wr * 64 + fm * 16 + ln;
                af[fm] = *(const short8*)(As + row * 64 + ((gg ^ (row & 7)) * 8));
            }
            #pragma unroll
            for (int fn = 0; fn < 4; ++fn) {
                int col = wc * 64 + fn * 16 + ln;
                bfr[fn] = *(const short8*)(Bs + col * 64 + ((gg ^ (col & 7)) * 8));
            }
            #pragma unroll
            for (int fm = 0; fm < 4; ++fm)
                #pragma unroll
                for (int fn = 0; fn < 4; ++fn)
                    acc[fm][fn] = __builtin_amdgcn_mfma_f32_16x16x32_bf16(
                        af[fm], bfr[fn], acc[fm][fn], 0, 0, 0);
        }
    }

    const float* bias = (proj == 0) ? bq : (proj == 1) ? bk : bv;
    #pragma unroll
    for (int fn = 0; fn < 4; ++fn) {
        int n = nBase + wc * 64 + fn * 16 + ln;
        int cc = n & (Ec - 1);
        int hh = cc >> 6, d = cc & 63;
        float bv_ = bias[cc];
        #pragma unroll
        for (int fm = 0; fm < 4; ++fm) {
            #pragma unroll
            for (int r = 0; r < 4; ++r) {
                int m = mBase + wr * 64 + fm * 16 + lq * 4 + r;
                int b = m >> 11, s = m & (Sc - 1);
                int bh = b * Hc + hh;
                float vv = acc[fm][fn][r] + bv_;
                // Q scaled by log2(e)/8 -> softmax in exp2 domain
                if (proj == 0)      qb[((size_t)bh * Sc + s) * DHc + d] = f2bf(vv * 0.18033688011f);
                else if (proj == 1) kb[((size_t)bh * Sc + s) * DHc + d] = f2bf(vv);
                else                vb[((size_t)bh * DHc + d) * Sc + s] = f2bf(vv);
            }
        }
    }
}

// ---------------------------------------------------------------------------
// Flash attention, bf16 MFMA, swapped-QK^T softmax.
// Block = 128 q-rows x (h, b); 4 waves, 32 q-rows each (2 groups of 16).
// S^T = mfma(K, Q): lane holds 16 keys for ONE q-column -> row-reduce is
// in-register + 2 shfl_xor. P packed to per-wave LDS (b64 swizzled), reread
// as PV A-operand. Defer-max (THR=8, log2 domain) skips O-rescale.
// ---------------------------------------------------------------------------
__global__ __launch_bounds__(256)
void attn_mfma_kernel(const u16* __restrict__ qb, const u16* __restrict__ kb,
                      const u16* __restrict__ vb, u16* __restrict__ concatb)
{
    __shared__ __align__(16) u16 Kt[64 * 64];
    __shared__ __align__(16) u16 Vt[64 * 64];
    __shared__ __align__(16) u16 Ps[4 * 32 * 64];   // per-wave [32 q][64 key]

    const int t = threadIdx.x;
    const int w = t >> 6, l = t & 63;
    const int qt = blockIdx.x, h = blockIdx.y, b = blockIdx.z;
    const int bh = b * Hc + h;
    const int lq = l >> 4, ln = l & 15;
    const int lr = l >> 3, ls = l & 7;
    const int sw = ln & 7;

    const u16* qp = qb + ((size_t)bh * Sc + qt * 128 + w * 32) * DHc;
    const u16* kp = kb + (size_t)bh * Sc * DHc;
    const u16* vp = vb + (size_t)bh * DHc * Sc;
    u16* pw = Ps + w * (32 * 64);

    // Q fragments (B-operand): col=q=ln (within q-group), k=d=lq*8 + ks*32
    short8 qf[2][2];
    #pragma unroll
    for (int qg = 0; qg < 2; ++qg)
        #pragma unroll
        for (int ks = 0; ks < 2; ++ks)
            qf[qg][ks] = *(const short8*)(qp + (qg * 16 + ln) * DHc + ks * 32 + lq * 8);

    f32x4 o[2][4];
    #pragma unroll
    for (int qg = 0; qg < 2; ++qg)
        #pragma unroll
        for (int fd = 0; fd < 4; ++fd) o[qg][fd] = (f32x4)0.f;
    float m_i[2] = {-1e30f, -1e30f}, l_i[2] = {0.f, 0.f};

    for (int kt = 0; kt < Sc / 64; ++kt) {
        __syncthreads();                     // all waves done reading prev K/V
        #pragma unroll
        for (int c = 0; c < 4; ++c) {
            int cg = w * 4 + c;
            if (cg < 8) {                    // K rows [key][d]
                int row = cg * 8 + lr;
                int g = ls ^ (row & 7);
                gl_lds16(kp + ((size_t)(kt * 64 + row)) * DHc + g * 8,
                         (void*)(Kt + cg * 512));
            } else {                         // V^T rows [d][key]
                int d = (cg - 8) * 8 + lr;
                int g = ls ^ (d & 7);
                gl_lds16(vp + (size_t)d * Sc + kt * 64 + g * 8,
                         (void*)(Vt + (cg - 8) * 512));
            }
        }
        __syncthreads();

        // ---- S^T = K Q^T : D[key][q], lane: q=ln, key = fn*16 + lq*4 + r
        f32x4 s[2][4];
        #pragma unroll
        for (int qg = 0; qg < 2; ++qg)
            #pragma unroll
            for (int fn = 0; fn < 4; ++fn) s[qg][fn] = (f32x4)0.f;
        #pragma unroll
        for (int ks = 0; ks < 2; ++ks) {
            int gg = ks * 4 + lq;
            #pragma unroll
            for (int fn = 0; fn < 4; ++fn) {
                int key = fn * 16 + ln;
                short8 kf = *(const short8*)(Kt + key * 64 + ((gg ^ sw) * 8));
                s[0][fn] = __builtin_amdgcn_mfma_f32_16x16x32_bf16(kf, qf[0][ks], s[0][fn], 0, 0, 0);
                s[1][fn] = __builtin_amdgcn_mfma_f32_16x16x32_bf16(kf, qf[1][ks], s[1][fn], 0, 0, 0);
            }
        }

        // ---- online softmax, log2 domain, per-lane over 16 in-reg keys
        float pmax[2];
        #pragma unroll
        for (int qg = 0; qg < 2; ++qg) {
            float m0 = fmaxf(fmaxf(s[qg][0][0], s[qg][0][1]), fmaxf(s[qg][0][2], s[qg][0][3]));
            float m1 = fmaxf(fmaxf(s[qg][1][0], s[qg][1][1]), fmaxf(s[qg][1][2], s[qg][1][3]));
            float m2 = fmaxf(fmaxf(s[qg][2][0], s[qg][2][1]), fmaxf(s[qg][2][2], s[qg][2][3]));
            float m3 = fmaxf(fmaxf(s[qg][3][0], s[qg][3][1]), fmaxf(s[qg][3][2], s[qg][3][3]));
            float mx = fmaxf(fmaxf(m0, m1), fmaxf(m2, m3));
            mx = fmaxf(mx, __shfl_xor(mx, 16));
            mx = fmaxf(mx, __shfl_xor(mx, 32));
            pmax[qg] = mx;
        }
        bool need = (pmax[0] > m_i[0] + 8.f) || (pmax[1] > m_i[1] + 8.f);
        if (__any(need)) {                   // rare: rescale O, update m
            #pragma unroll
            for (int qg = 0; qg < 2; ++qg) {
                float nm = fmaxf(m_i[qg], pmax[qg]);
                float ef = exp2f(m_i[qg] - nm);
                l_i[qg] *= ef;
                m_i[qg] = nm;
                #pragma unroll
                for (int r = 0; r < 4; ++r) {
                    float efr = __shfl(ef, lq * 4 + r);   // ef of row q=lq*4+r
                    #pragma unroll
                    for (int fd = 0; fd < 4; ++fd) o[qg][fd][r] *= efr;
                }
            }
        }
        #pragma unroll
        for (int qg = 0; qg < 2; ++qg) {
            float p[4][4];
            float sum = 0.f;
            #pragma unroll
            for (int fn = 0; fn < 4; ++fn)
                #pragma unroll
                for (int r = 0; r < 4; ++r) {
                    p[fn][r] = exp2f(s[qg][fn][r] - m_i[qg]);
                    sum += p[fn][r];
                }
            sum += __shfl_xor(sum, 16);
            sum += __shfl_xor(sum, 32);
            l_i[qg] += sum;
            // pack pairs, write P[q][key] (b64, 16B-slot swizzled by q&7)
            #pragma unroll
            for (int fn = 0; fn < 4; ++fn) {
                unsigned int pa, pb;
                asm("v_cvt_pk_bf16_f32 %0, %1, %2" : "=v"(pa) : "v"(p[fn][0]), "v"(p[fn][1]));
                asm("v_cvt_pk_bf16_f32 %0, %1, %2" : "=v"(pb) : "v"(p[fn][2]), "v"(p[fn][3]));
                uint2 u; u.x = pa; u.y = pb;
                *(uint2*)(pw + (qg * 16 + ln) * 64 +
                          (((2 * fn + (lq >> 1)) ^ sw) << 3) + (lq & 1) * 4) = u;
            }
        }
        asm volatile("s_waitcnt lgkmcnt(0)" ::: "memory");

        // ---- O += P V : A = P[q][key] (reread), B = V[key][d] via Vt[d][key]
        #pragma unroll
        for (int c = 0; c < 2; ++c) {
            int gg = c * 4 + lq;
            short8 pf0 = *(const short8*)(pw + ln * 64 + ((gg ^ sw) << 3));
            short8 pf1 = *(const short8*)(pw + (16 + ln) * 64 + ((gg ^ sw) << 3));
            #pragma unroll
            for (int fd = 0; fd < 4; ++fd) {
                int d = fd * 16 + ln;
                short8 vf = *(const short8*)(Vt + d * 64 + ((gg ^ sw) << 3));
                o[0][fd] = __builtin_amdgcn_mfma_f32_16x16x32_bf16(pf0, vf, o[0][fd], 0, 0, 0);
                o[1][fd] = __builtin_amdgcn_mfma_f32_16x16x32_bf16(pf1, vf, o[1][fd], 0, 0, 0);
            }
        }
    }

    // ---- epilogue: normalize by row-l (pulled via shfl), write concat bf16
    #pragma unroll
    for (int qg = 0; qg < 2; ++qg) {
        #pragma unroll
        for (int r = 0; r < 4; ++r) {
            float lr_ = __shfl(l_i[qg], lq * 4 + r);
            float inv = 1.f / lr_;
            int q = qt * 128 + w * 32 + qg * 16 + lq * 4 + r;
            #pragma unroll
            for (int fd = 0; fd < 4; ++fd) {
                int d = h * DHc + fd * 16 + ln;
                concatb[((size_t)b * Sc + q) * Ec + d] = f2bf(o[qg][fd][r] * inv);
            }
        }
    }
}

// ---------------------------------------------------------------------------
// Output projection GEMM (bf16 MFMA): out[m][n] = concat[m][:] . Wo[n][:] + bo
// ---------------------------------------------------------------------------
__global__ __launch_bounds__(256)
void oproj_mfma_kernel(const u16* __restrict__ cb, const u16* __restrict__ Wob,
                       const float* __restrict__ bo, float* __restrict__ out)
{
    __shared__ __align__(16) u16 As[128 * 64];
    __shared__ __align__(16) u16 Bs[128 * 64];

    const int t = threadIdx.x;
    const int w = t >> 6, l = t & 63;
    const int wr = w >> 1, wc = w & 1;
    const int mBase = blockIdx.y * 128;
    const int nBase = blockIdx.x * 128;
    const int lr = l >> 3, ls = l & 7;
    const int lq = l >> 4, ln = l & 15;

    f32x4 acc[4][4];
    #pragma unroll
    for (int i = 0; i < 4; ++i)
        #pragma unroll
        for (int j = 0; j < 4; ++j) acc[i][j] = (f32x4)0.f;

    for (int k0 = 0; k0 < Ec; k0 += 64) {
        __syncthreads();
        #pragma unroll
        for (int c = 0; c < 8; ++c) {
            int cg = w * 8 + c;
            if (cg < 16) {
                int row = cg * 8 + lr;
                int g = ls ^ (row & 7);
                gl_lds16(cb + ((size_t)(mBase + row)) * Ec + k0 + g * 8,
                         (void*)(As + cg * 512));
            } else {
                int col = (cg - 16) * 8 + lr;
                int g = ls ^ (col & 7);
                gl_lds16(Wob + ((size_t)(nBase + col)) * Ec + k0 + g * 8,
                         (void*)(Bs + (cg - 16) * 512));
            }
        }
        __syncthreads();

        #pragma unroll
        for (int ks = 0; ks < 2; ++ks) {
            short8 af[4], bfr[4];
            int gg = ks * 4 + lq;
            #pragma unroll
            for (int fm = 0; fm < 4; ++fm) {
                int row = wr * 64 + fm * 16 + ln;
                af[fm] = *(const short8*)(As + row * 64 + ((gg ^ (row & 7)) * 8));
            }
            #pragma unroll
            for (int fn = 0; fn < 4; ++fn) {
                int col = wc * 64 + fn * 16 + ln;
                bfr[fn] = *(const short8*)(Bs + col * 64 + ((gg ^ (col & 7)) * 8));
            }
            #pragma unroll
            for (int fm = 0; fm < 4; ++fm)
                #pragma unroll
                for (int fn = 0; fn < 4; ++fn)
                    acc[fm][fn] = __builtin_amdgcn_mfma_f32_16x16x32_bf16(
                        af[fm], bfr[fn], acc[fm][fn], 0, 0, 0);
        }
    }

    #pragma unroll
    for (int fn = 0; fn < 4; ++fn) {
        int n = nBase + wc * 64 + fn * 16 + ln;
        float bb = bo[n];
        #pragma unroll
        for (int fm = 0; fm < 4; ++fm) {
            #pragma unroll
            for (int r = 0; r < 4; ++r) {
                int m = mBase + wr * 64 + fm * 16 + lq * 4 + r;
                out[(size_t)m * Ec + n] = acc[fm][fn][r] + bb;
            }
        }
    }
}

// ---------------------------------------------------------------------------
extern "C" void kernel_launch(void* const* d_in, const int* in_sizes, int n_in,
                              void* d_out, int out_size, void* d_ws, size_t ws_size,
                              hipStream_t stream)
{
    const float* x  = (const float*)d_in[0];
    const float* Wq = (const float*)d_in[1];
    const float* bq = (const float*)d_in[2];
    const float* Wk = (const float*)d_in[3];
    const float* bk = (const float*)d_in[4];
    const float* Wv = (const float*)d_in[5];
    const float* bv = (const float*)d_in[6];
    const float* Wo = (const float*)d_in[7];
    const float* bo = (const float*)d_in[8];
    float* out = (float*)d_out;

    char* ws = (char*)d_ws;
    u16* xb   = (u16*)(ws);                   // 16 MB  [8192][1024]
    u16* Wtb  = (u16*)(ws + (16u << 20));     //  6 MB  [3*1024][1024]
    u16* Wob  = (u16*)(ws + (22u << 20));     //  2 MB  [1024][1024]
    u16* qbuf = (u16*)(ws + (24u << 20));     // 16 MB  [bh][s][d], pre-scaled log2e/8
    u16* kbuf = (u16*)(ws + (40u << 20));     // 16 MB  [bh][s][d]
    u16* vbuf = (u16*)(ws + (56u << 20));     // 16 MB  [bh][d][s]  (transposed)
    u16* cbuf = (u16*)(ws + (72u << 20));     // 16 MB  [b][s][e]

    cast_bf16_kernel<<<(Bc * Sc * Ec / 8 + 255) / 256, 256, 0, stream>>>(x, xb, Bc * Sc * Ec / 8);
    cast_bf16_kernel<<<(Ec * Ec / 8 + 255) / 256, 256, 0, stream>>>(Wo, Wob, Ec * Ec / 8);
    dim3 gt(Ec / 64, Hc, 3);
    transW_kernel<<<gt, 256, 0, stream>>>(Wq, Wk, Wv, Wtb);

    dim3 g1(3 * Ec / 128, (Bc * Sc) / 128);   // (24, 64)
    qkv_mfma_kernel<<<g1, 256, 0, stream>>>(xb, Wtb, bq, bk, bv, qbuf, kbuf, vbuf);

    dim3 g2(Sc / 128, Hc, Bc);                // (16, 16, 4)
    attn_mfma_kernel<<<g2, 256, 0, stream>>>(qbuf, kbuf, vbuf, cbuf);

    dim3 g3(Ec / 128, (Bc * Sc) / 128);       // (8, 64)
    oproj_mfma_kernel<<<g3, 256, 0, stream>>>(cbuf, Wob, bo, out);
}

// Round 4
// 281.712 us; speedup vs baseline: 7.8651x; 1.0260x over previous
//
#include <hip/hip_runtime.h>
#include <math.h>

#define Bc 4
#define Sc 2048
#define Ec 1024
#define Hc 16
#define DHc 64

typedef unsigned short u16;
typedef __attribute__((ext_vector_type(8))) short short8;   // 8 bf16 = 4 VGPR
typedef __attribute__((ext_vector_type(4))) float f32x4;
typedef __attribute__((ext_vector_type(2))) unsigned short u16x2;

__device__ __forceinline__ u16 f2bf(float f) {
    unsigned int u = __float_as_uint(f);
    u += 0x7FFFu + ((u >> 16) & 1u);          // round-to-nearest-even
    return (u16)(u >> 16);
}

// global -> LDS direct copy, 16B per lane. LDS dest is wave-uniform base
// (+ lane*16 implicit); global src is per-lane.
__device__ __forceinline__ void gl_lds16(const void* g, void* l) {
    __builtin_amdgcn_global_load_lds(
        (const __attribute__((address_space(1))) unsigned int*)g,
        (__attribute__((address_space(3))) unsigned int*)l,
        16, 0, 0);
}

// ---------------------------------------------------------------------------
// cast fp32 -> bf16, 8 elems/thread
// ---------------------------------------------------------------------------
__global__ __launch_bounds__(256)
void cast_bf16_kernel(const float* __restrict__ in, u16* __restrict__ out, int n8)
{
    int i = blockIdx.x * 256 + threadIdx.x;
    if (i >= n8) return;
    const float* p = in + (size_t)i * 8;
    float4 a = *(const float4*)p;
    float4 b = *(const float4*)(p + 4);
    short8 v;
    v[0] = (short)f2bf(a.x); v[1] = (short)f2bf(a.y);
    v[2] = (short)f2bf(a.z); v[3] = (short)f2bf(a.w);
    v[4] = (short)f2bf(b.x); v[5] = (short)f2bf(b.y);
    v[6] = (short)f2bf(b.z); v[7] = (short)f2bf(b.w);
    *(short8*)(out + (size_t)i * 8) = v;
}

// ---------------------------------------------------------------------------
// transpose+cast W[proj][h][e][d] fp32 -> Wtb[(proj*16+h)*64+d][e] bf16
// ---------------------------------------------------------------------------
__global__ __launch_bounds__(256)
void transW_kernel(const float* __restrict__ Wq, const float* __restrict__ Wk,
                   const float* __restrict__ Wv, u16* __restrict__ Wtb)
{
    __shared__ float T[64][65];
    const int t = threadIdx.x;
    const int e0 = blockIdx.x * 64;
    const int h = blockIdx.y;
    const int proj = blockIdx.z;
    const float* W = (proj == 0) ? Wq : (proj == 1) ? Wk : Wv;

    #pragma unroll
    for (int i = 0; i < 4; ++i) {
        int fid = t + i * 256;
        int row = fid >> 4, c4 = fid & 15;
        float4 v = *(const float4*)(W + ((size_t)h * Ec + e0 + row) * DHc + c4 * 4);
        T[row][c4 * 4 + 0] = v.x; T[row][c4 * 4 + 1] = v.y;
        T[row][c4 * 4 + 2] = v.z; T[row][c4 * 4 + 3] = v.w;
    }
    __syncthreads();
    const int d = t >> 2, ech = (t & 3) * 16;
    u16* dst = Wtb + ((size_t)(proj * Hc + h) * DHc + d) * Ec + e0 + ech;
    #pragma unroll
    for (int j = 0; j < 16; j += 2) {
        u16x2 v2;
        v2.x = f2bf(T[ech + j][d]);
        v2.y = f2bf(T[ech + j + 1][d]);
        *(u16x2*)(dst + j) = v2;
    }
}

// ---------------------------------------------------------------------------
// QKV projection GEMM (bf16 MFMA): M=8192, N=3072, K=1024.
// Q output pre-scaled by log2(e)/sqrt(DH) so attn softmax runs in exp2 domain.
// ---------------------------------------------------------------------------
__global__ __launch_bounds__(256)
void qkv_mfma_kernel(const u16* __restrict__ xb, const u16* __restrict__ Wtb,
                     const float* __restrict__ bq, const float* __restrict__ bk,
                     const float* __restrict__ bv,
                     u16* __restrict__ qb, u16* __restrict__ kb, u16* __restrict__ vb)
{
    __shared__ __align__(16) u16 As[128 * 64];
    __shared__ __align__(16) u16 Bs[128 * 64];

    const int t = threadIdx.x;
    const int w = t >> 6, l = t & 63;
    const int wr = w >> 1, wc = w & 1;
    const int mBase = blockIdx.y * 128;
    const int nBase = blockIdx.x * 128;
    const int proj = nBase >> 10;            // block never straddles a proj
    const int nIn = nBase & (Ec - 1);
    const int lr = l >> 3, ls = l & 7;
    const int lq = l >> 4, ln = l & 15;

    f32x4 acc[4][4];
    #pragma unroll
    for (int i = 0; i < 4; ++i)
        #pragma unroll
        for (int j = 0; j < 4; ++j) acc[i][j] = (f32x4)0.f;

    for (int k0 = 0; k0 < Ec; k0 += 64) {
        __syncthreads();
        #pragma unroll
        for (int c = 0; c < 8; ++c) {
            int cg = w * 8 + c;
            if (cg < 16) {                   // A rows
                int row = cg * 8 + lr;
                int g = ls ^ (row & 7);
                gl_lds16(xb + ((size_t)(mBase + row)) * Ec + k0 + g * 8,
                         (void*)(As + cg * 512));
            } else {                         // B cols (Wtb rows)
                int col = (cg - 16) * 8 + lr;
                int g = ls ^ (col & 7);
                gl_lds16(Wtb + ((size_t)proj * Ec + nIn + col) * Ec + k0 + g * 8,
                         (void*)(Bs + (cg - 16) * 512));
            }
        }
        __syncthreads();

        #pragma unroll
        for (int ks = 0; ks < 2; ++ks) {
            short8 af[4], bfr[4];
            int gg = ks * 4 + lq;
            #pragma unroll
            for (int fm = 0; fm < 4; ++fm) {
                int row = wr * 64 + fm * 16 + ln;
                af[fm] = *(const short8*)(As + row * 64 + ((gg ^ (row & 7)) * 8));
            }
            #pragma unroll
            for (int fn = 0; fn < 4; ++fn) {
                int col = wc * 64 + fn * 16 + ln;
                bfr[fn] = *(const short8*)(Bs + col * 64 + ((gg ^ (col & 7)) * 8));
            }
            #pragma unroll
            for (int fm = 0; fm < 4; ++fm)
                #pragma unroll
                for (int fn = 0; fn < 4; ++fn)
                    acc[fm][fn] = __builtin_amdgcn_mfma_f32_16x16x32_bf16(
                        af[fm], bfr[fn], acc[fm][fn], 0, 0, 0);
        }
    }

    const float* bias = (proj == 0) ? bq : (proj == 1) ? bk : bv;
    #pragma unroll
    for (int fn = 0; fn < 4; ++fn) {
        int n = nBase + wc * 64 + fn * 16 + ln;
        int cc = n & (Ec - 1);
        int hh = cc >> 6, d = cc & 63;
        float bv_ = bias[cc];
        #pragma unroll
        for (int fm = 0; fm < 4; ++fm) {
            #pragma unroll
            for (int r = 0; r < 4; ++r) {
                int m = mBase + wr * 64 + fm * 16 + lq * 4 + r;
                int b = m >> 11, s = m & (Sc - 1);
                int bh = b * Hc + hh;
                float vv = acc[fm][fn][r] + bv_;
                // Q scaled by log2(e)/8 -> softmax in exp2 domain
                if (proj == 0)      qb[((size_t)bh * Sc + s) * DHc + d] = f2bf(vv * 0.18033688011f);
                else if (proj == 1) kb[((size_t)bh * Sc + s) * DHc + d] = f2bf(vv);
                else                vb[((size_t)bh * DHc + d) * Sc + s] = f2bf(vv);
            }
        }
    }
}

// ---------------------------------------------------------------------------
// Flash attention, bf16 MFMA, swapped-QK^T softmax, double-buffered K/V.
// Block = 128 q-rows x (h, b); 4 waves, 32 q-rows each (2 groups of 16).
// Stage(kt+1) issued FIRST in iteration kt -> HBM/L2 latency hides under
// QK^T+softmax+PV of tile kt; single vmcnt(0)+barrier per tile.
// ---------------------------------------------------------------------------
__global__ __launch_bounds__(256)
void attn_mfma_kernel(const u16* __restrict__ qb, const u16* __restrict__ kb,
                      const u16* __restrict__ vb, u16* __restrict__ concatb)
{
    __shared__ __align__(16) u16 Kt[2][64 * 64];
    __shared__ __align__(16) u16 Vt[2][64 * 64];
    __shared__ __align__(16) u16 Ps[4 * 32 * 64];   // per-wave [32 q][64 key]

    const int t = threadIdx.x;
    const int w = t >> 6, l = t & 63;
    const int qt = blockIdx.x, h = blockIdx.y, b = blockIdx.z;
    const int bh = b * Hc + h;
    const int lq = l >> 4, ln = l & 15;
    const int lr = l >> 3, ls = l & 7;
    const int sw = ln & 7;

    const u16* qp = qb + ((size_t)bh * Sc + qt * 128 + w * 32) * DHc;
    const u16* kp = kb + (size_t)bh * Sc * DHc;
    const u16* vp = vb + (size_t)bh * DHc * Sc;
    u16* pw = Ps + w * (32 * 64);

    // per-wave staging: 4 global_load_lds of 16B x 64 lanes (2 K-chunks or 2 V-chunks)
    const int cg = w * 4;   // this wave's first chunk id (0..15)

    // Q fragments (B-operand): col=q=ln (within q-group), k=d=lq*8 + ks*32
    short8 qf[2][2];
    #pragma unroll
    for (int qg = 0; qg < 2; ++qg)
        #pragma unroll
        for (int ks = 0; ks < 2; ++ks)
            qf[qg][ks] = *(const short8*)(qp + (qg * 16 + ln) * DHc + ks * 32 + lq * 8);

    f32x4 o[2][4];
    #pragma unroll
    for (int qg = 0; qg < 2; ++qg)
        #pragma unroll
        for (int fd = 0; fd < 4; ++fd) o[qg][fd] = (f32x4)0.f;
    float m_i[2] = {-1e30f, -1e30f}, l_i[2] = {0.f, 0.f};

    // ---- prologue: stage tile 0 into buffer 0
    #pragma unroll
    for (int c = 0; c < 4; ++c) {
        int g2 = cg + c;
        if (g2 < 8) {
            int row = g2 * 8 + lr;
            int g = ls ^ (row & 7);
            gl_lds16(kp + ((size_t)row) * DHc + g * 8, (void*)(Kt[0] + g2 * 512));
        } else {
            int d = (g2 - 8) * 8 + lr;
            int g = ls ^ (d & 7);
            gl_lds16(vp + (size_t)d * Sc + g * 8, (void*)(Vt[0] + (g2 - 8) * 512));
        }
    }
    asm volatile("s_waitcnt vmcnt(0)" ::: "memory");
    __syncthreads();

    for (int kt = 0; kt < Sc / 64; ++kt) {
        const int cur = kt & 1;
        // ---- prefetch next tile into the other buffer (latency hides under compute)
        if (kt + 1 < Sc / 64) {
            const int nxt = cur ^ 1;
            #pragma unroll
            for (int c = 0; c < 4; ++c) {
                int g2 = cg + c;
                if (g2 < 8) {
                    int row = g2 * 8 + lr;
                    int g = ls ^ (row & 7);
                    gl_lds16(kp + ((size_t)((kt + 1) * 64 + row)) * DHc + g * 8,
                             (void*)(Kt[nxt] + g2 * 512));
                } else {
                    int d = (g2 - 8) * 8 + lr;
                    int g = ls ^ (d & 7);
                    gl_lds16(vp + (size_t)d * Sc + (kt + 1) * 64 + g * 8,
                             (void*)(Vt[nxt] + (g2 - 8) * 512));
                }
            }
        }

        // ---- S^T = K Q^T : D[key][q], lane: q=ln, key = fn*16 + lq*4 + r
        f32x4 s[2][4];
        #pragma unroll
        for (int qg = 0; qg < 2; ++qg)
            #pragma unroll
            for (int fn = 0; fn < 4; ++fn) s[qg][fn] = (f32x4)0.f;
        __builtin_amdgcn_s_setprio(1);
        #pragma unroll
        for (int ks = 0; ks < 2; ++ks) {
            int gg = ks * 4 + lq;
            #pragma unroll
            for (int fn = 0; fn < 4; ++fn) {
                int key = fn * 16 + ln;
                short8 kf = *(const short8*)(Kt[cur] + key * 64 + ((gg ^ sw) * 8));
                s[0][fn] = __builtin_amdgcn_mfma_f32_16x16x32_bf16(kf, qf[0][ks], s[0][fn], 0, 0, 0);
                s[1][fn] = __builtin_amdgcn_mfma_f32_16x16x32_bf16(kf, qf[1][ks], s[1][fn], 0, 0, 0);
            }
        }
        __builtin_amdgcn_s_setprio(0);

        // ---- online softmax, log2 domain, per-lane over 16 in-reg keys
        float pmax[2];
        #pragma unroll
        for (int qg = 0; qg < 2; ++qg) {
            float m0 = fmaxf(fmaxf(s[qg][0][0], s[qg][0][1]), fmaxf(s[qg][0][2], s[qg][0][3]));
            float m1 = fmaxf(fmaxf(s[qg][1][0], s[qg][1][1]), fmaxf(s[qg][1][2], s[qg][1][3]));
            float m2 = fmaxf(fmaxf(s[qg][2][0], s[qg][2][1]), fmaxf(s[qg][2][2], s[qg][2][3]));
            float m3 = fmaxf(fmaxf(s[qg][3][0], s[qg][3][1]), fmaxf(s[qg][3][2], s[qg][3][3]));
            float mx = fmaxf(fmaxf(m0, m1), fmaxf(m2, m3));
            mx = fmaxf(mx, __shfl_xor(mx, 16));
            mx = fmaxf(mx, __shfl_xor(mx, 32));
            pmax[qg] = mx;
        }
        bool need = (pmax[0] > m_i[0] + 8.f) || (pmax[1] > m_i[1] + 8.f);
        if (__any(need)) {                   // rare: rescale O, update m
            #pragma unroll
            for (int qg = 0; qg < 2; ++qg) {
                float nm = fmaxf(m_i[qg], pmax[qg]);
                float ef = exp2f(m_i[qg] - nm);
                l_i[qg] *= ef;
                m_i[qg] = nm;
                #pragma unroll
                for (int r = 0; r < 4; ++r) {
                    float efr = __shfl(ef, lq * 4 + r);   // ef of row q=lq*4+r
                    #pragma unroll
                    for (int fd = 0; fd < 4; ++fd) o[qg][fd][r] *= efr;
                }
            }
        }
        #pragma unroll
        for (int qg = 0; qg < 2; ++qg) {
            float p[4][4];
            float sum = 0.f;
            #pragma unroll
            for (int fn = 0; fn < 4; ++fn)
                #pragma unroll
                for (int r = 0; r < 4; ++r) {
                    p[fn][r] = exp2f(s[qg][fn][r] - m_i[qg]);
                    sum += p[fn][r];
                }
            sum += __shfl_xor(sum, 16);
            sum += __shfl_xor(sum, 32);
            l_i[qg] += sum;
            // pack pairs, write P[q][key] (b64, 16B-slot swizzled by q&7)
            #pragma unroll
            for (int fn = 0; fn < 4; ++fn) {
                unsigned int pa, pb;
                asm("v_cvt_pk_bf16_f32 %0, %1, %2" : "=v"(pa) : "v"(p[fn][0]), "v"(p[fn][1]));
                asm("v_cvt_pk_bf16_f32 %0, %1, %2" : "=v"(pb) : "v"(p[fn][2]), "v"(p[fn][3]));
                uint2 u; u.x = pa; u.y = pb;
                *(uint2*)(pw + (qg * 16 + ln) * 64 +
                          (((2 * fn + (lq >> 1)) ^ sw) << 3) + (lq & 1) * 4) = u;
            }
        }
        asm volatile("s_waitcnt lgkmcnt(0)" ::: "memory");

        // ---- O += P V : A = P[q][key] (reread), B = V[key][d] via Vt[d][key]
        __builtin_amdgcn_s_setprio(1);
        #pragma unroll
        for (int c = 0; c < 2; ++c) {
            int gg = c * 4 + lq;
            short8 pf0 = *(const short8*)(pw + ln * 64 + ((gg ^ sw) << 3));
            short8 pf1 = *(const short8*)(pw + (16 + ln) * 64 + ((gg ^ sw) << 3));
            #pragma unroll
            for (int fd = 0; fd < 4; ++fd) {
                int d = fd * 16 + ln;
                short8 vf = *(const short8*)(Vt[cur] + d * 64 + ((gg ^ sw) << 3));
                o[0][fd] = __builtin_amdgcn_mfma_f32_16x16x32_bf16(pf0, vf, o[0][fd], 0, 0, 0);
                o[1][fd] = __builtin_amdgcn_mfma_f32_16x16x32_bf16(pf1, vf, o[1][fd], 0, 0, 0);
            }
        }
        __builtin_amdgcn_s_setprio(0);

        // ---- next tile's loads complete; all waves done reading cur buffers
        asm volatile("s_waitcnt vmcnt(0)" ::: "memory");
        __syncthreads();
    }

    // ---- epilogue: normalize by row-l (pulled via shfl), write concat bf16
    #pragma unroll
    for (int qg = 0; qg < 2; ++qg) {
        #pragma unroll
        for (int r = 0; r < 4; ++r) {
            float lr_ = __shfl(l_i[qg], lq * 4 + r);
            float inv = 1.f / lr_;
            int q = qt * 128 + w * 32 + qg * 16 + lq * 4 + r;
            #pragma unroll
            for (int fd = 0; fd < 4; ++fd) {
                int d = h * DHc + fd * 16 + ln;
                concatb[((size_t)b * Sc + q) * Ec + d] = f2bf(o[qg][fd][r] * inv);
            }
        }
    }
}

// ---------------------------------------------------------------------------
// Output projection GEMM (bf16 MFMA): out[m][n] = concat[m][:] . Wo[n][:] + bo
// ---------------------------------------------------------------------------
__global__ __launch_bounds__(256)
void oproj_mfma_kernel(const u16* __restrict__ cb, const u16* __restrict__ Wob,
                       const float* __restrict__ bo, float* __restrict__ out)
{
    __shared__ __align__(16) u16 As[128 * 64];
    __shared__ __align__(16) u16 Bs[128 * 64];

    const int t = threadIdx.x;
    const int w = t >> 6, l = t & 63;
    const int wr = w >> 1, wc = w & 1;
    const int mBase = blockIdx.y * 128;
    const int nBase = blockIdx.x * 128;
    const int lr = l >> 3, ls = l & 7;
    const int lq = l >> 4, ln = l & 15;

    f32x4 acc[4][4];
    #pragma unroll
    for (int i = 0; i < 4; ++i)
        #pragma unroll
        for (int j = 0; j < 4; ++j) acc[i][j] = (f32x4)0.f;

    for (int k0 = 0; k0 < Ec; k0 += 64) {
        __syncthreads();
        #pragma unroll
        for (int c = 0; c < 8; ++c) {
            int cg = w * 8 + c;
            if (cg < 16) {
                int row = cg * 8 + lr;
                int g = ls ^ (row & 7);
                gl_lds16(cb + ((size_t)(mBase + row)) * Ec + k0 + g * 8,
                         (void*)(As + cg * 512));
            } else {
                int col = (cg - 16) * 8 + lr;
                int g = ls ^ (col & 7);
                gl_lds16(Wob + ((size_t)(nBase + col)) * Ec + k0 + g * 8,
                         (void*)(Bs + (cg - 16) * 512));
            }
        }
        __syncthreads();

        #pragma unroll
        for (int ks = 0; ks < 2; ++ks) {
            short8 af[4], bfr[4];
            int gg = ks * 4 + lq;
            #pragma unroll
            for (int fm = 0; fm < 4; ++fm) {
                int row = wr * 64 + fm * 16 + ln;
                af[fm] = *(const short8*)(As + row * 64 + ((gg ^ (row & 7)) * 8));
            }
            #pragma unroll
            for (int fn = 0; fn < 4; ++fn) {
                int col = wc * 64 + fn * 16 + ln;
                bfr[fn] = *(const short8*)(Bs + col * 64 + ((gg ^ (col & 7)) * 8));
            }
            #pragma unroll
            for (int fm = 0; fm < 4; ++fm)
                #pragma unroll
                for (int fn = 0; fn < 4; ++fn)
                    acc[fm][fn] = __builtin_amdgcn_mfma_f32_16x16x32_bf16(
                        af[fm], bfr[fn], acc[fm][fn], 0, 0, 0);
        }
    }

    #pragma unroll
    for (int fn = 0; fn < 4; ++fn) {
        int n = nBase + wc * 64 + fn * 16 + ln;
        float bb = bo[n];
        #pragma unroll
        for (int fm = 0; fm < 4; ++fm) {
            #pragma unroll
            for (int r = 0; r < 4; ++r) {
                int m = mBase + wr * 64 + fm * 16 + lq * 4 + r;
                out[(size_t)m * Ec + n] = acc[fm][fn][r] + bb;
            }
        }
    }
}

// ---------------------------------------------------------------------------
extern "C" void kernel_launch(void* const* d_in, const int* in_sizes, int n_in,
                              void* d_out, int out_size, void* d_ws, size_t ws_size,
                              hipStream_t stream)
{
    const float* x  = (const float*)d_in[0];
    const float* Wq = (const float*)d_in[1];
    const float* bq = (const float*)d_in[2];
    const float* Wk = (const float*)d_in[3];
    const float* bk = (const float*)d_in[4];
    const float* Wv = (const float*)d_in[5];
    const float* bv = (const float*)d_in[6];
    const float* Wo = (const float*)d_in[7];
    const float* bo = (const float*)d_in[8];
    float* out = (float*)d_out;

    char* ws = (char*)d_ws;
    u16* xb   = (u16*)(ws);                   // 16 MB  [8192][1024]
    u16* Wtb  = (u16*)(ws + (16u << 20));     //  6 MB  [3*1024][1024]
    u16* Wob  = (u16*)(ws + (22u << 20));     //  2 MB  [1024][1024]
    u16* qbuf = (u16*)(ws + (24u << 20));     // 16 MB  [bh][s][d], pre-scaled log2e/8
    u16* kbuf = (u16*)(ws + (40u << 20));     // 16 MB  [bh][s][d]
    u16* vbuf = (u16*)(ws + (56u << 20));     // 16 MB  [bh][d][s]  (transposed)
    u16* cbuf = (u16*)(ws + (72u << 20));     // 16 MB  [b][s][e]

    cast_bf16_kernel<<<(Bc * Sc * Ec / 8 + 255) / 256, 256, 0, stream>>>(x, xb, Bc * Sc * Ec / 8);
    cast_bf16_kernel<<<(Ec * Ec / 8 + 255) / 256, 256, 0, stream>>>(Wo, Wob, Ec * Ec / 8);
    dim3 gt(Ec / 64, Hc, 3);
    transW_kernel<<<gt, 256, 0, stream>>>(Wq, Wk, Wv, Wtb);

    dim3 g1(3 * Ec / 128, (Bc * Sc) / 128);   // (24, 64)
    qkv_mfma_kernel<<<g1, 256, 0, stream>>>(xb, Wtb, bq, bk, bv, qbuf, kbuf, vbuf);

    dim3 g2(Sc / 128, Hc, Bc);                // (16, 16, 4)
    attn_mfma_kernel<<<g2, 256, 0, stream>>>(qbuf, kbuf, vbuf, cbuf);

    dim3 g3(Ec / 128, (Bc * Sc) / 128);       // (8, 64)
    oproj_mfma_kernel<<<g3, 256, 0, stream>>>(cbuf, Wob, bo, out);
}

// Round 5
// 262.787 us; speedup vs baseline: 8.4315x; 1.0720x over previous
//
#include <hip/hip_runtime.h>
#include <math.h>

#define Bc 4
#define Sc 2048
#define Ec 1024
#define Hc 16
#define DHc 64

typedef unsigned short u16;
typedef __attribute__((ext_vector_type(8))) short short8;   // 8 bf16 = 4 VGPR
typedef __attribute__((ext_vector_type(4))) float f32x4;
typedef __attribute__((ext_vector_type(2))) unsigned short u16x2;

__device__ __forceinline__ u16 f2bf(float f) {
    unsigned int u = __float_as_uint(f);
    u += 0x7FFFu + ((u >> 16) & 1u);          // round-to-nearest-even
    return (u16)(u >> 16);
}

// global -> LDS direct copy, 16B per lane. LDS dest is wave-uniform base
// (+ lane*16 implicit); global src is per-lane.
__device__ __forceinline__ void gl_lds16(const void* g, void* l) {
    __builtin_amdgcn_global_load_lds(
        (const __attribute__((address_space(1))) unsigned int*)g,
        (__attribute__((address_space(3))) unsigned int*)l,
        16, 0, 0);
}

// ---------------------------------------------------------------------------
// cast fp32 -> bf16, 8 elems/thread
// ---------------------------------------------------------------------------
__global__ __launch_bounds__(256)
void cast_bf16_kernel(const float* __restrict__ in, u16* __restrict__ out, int n8)
{
    int i = blockIdx.x * 256 + threadIdx.x;
    if (i >= n8) return;
    const float* p = in + (size_t)i * 8;
    float4 a = *(const float4*)p;
    float4 b = *(const float4*)(p + 4);
    short8 v;
    v[0] = (short)f2bf(a.x); v[1] = (short)f2bf(a.y);
    v[2] = (short)f2bf(a.z); v[3] = (short)f2bf(a.w);
    v[4] = (short)f2bf(b.x); v[5] = (short)f2bf(b.y);
    v[6] = (short)f2bf(b.z); v[7] = (short)f2bf(b.w);
    *(short8*)(out + (size_t)i * 8) = v;
}

// ---------------------------------------------------------------------------
// transpose+cast W[proj][h][e][d] fp32 -> Wtb[(proj*16+h)*64+d][e] bf16
// ---------------------------------------------------------------------------
__global__ __launch_bounds__(256)
void transW_kernel(const float* __restrict__ Wq, const float* __restrict__ Wk,
                   const float* __restrict__ Wv, u16* __restrict__ Wtb)
{
    __shared__ float T[64][65];
    const int t = threadIdx.x;
    const int e0 = blockIdx.x * 64;
    const int h = blockIdx.y;
    const int proj = blockIdx.z;
    const float* W = (proj == 0) ? Wq : (proj == 1) ? Wk : Wv;

    #pragma unroll
    for (int i = 0; i < 4; ++i) {
        int fid = t + i * 256;
        int row = fid >> 4, c4 = fid & 15;
        float4 v = *(const float4*)(W + ((size_t)h * Ec + e0 + row) * DHc + c4 * 4);
        T[row][c4 * 4 + 0] = v.x; T[row][c4 * 4 + 1] = v.y;
        T[row][c4 * 4 + 2] = v.z; T[row][c4 * 4 + 3] = v.w;
    }
    __syncthreads();
    const int d = t >> 2, ech = (t & 3) * 16;
    u16* dst = Wtb + ((size_t)(proj * Hc + h) * DHc + d) * Ec + e0 + ech;
    #pragma unroll
    for (int j = 0; j < 16; j += 2) {
        u16x2 v2;
        v2.x = f2bf(T[ech + j][d]);
        v2.y = f2bf(T[ech + j + 1][d]);
        *(u16x2*)(dst + j) = v2;
    }
}

// ---------------------------------------------------------------------------
// QKV projection GEMM (bf16 MFMA): M=8192, N=3072, K=1024.
// Q output pre-scaled by log2(e)/sqrt(DH) so attn softmax runs in exp2 domain.
// ---------------------------------------------------------------------------
__global__ __launch_bounds__(256)
void qkv_mfma_kernel(const u16* __restrict__ xb, const u16* __restrict__ Wtb,
                     const float* __restrict__ bq, const float* __restrict__ bk,
                     const float* __restrict__ bv,
                     u16* __restrict__ qb, u16* __restrict__ kb, u16* __restrict__ vb)
{
    __shared__ __align__(16) u16 As[128 * 64];
    __shared__ __align__(16) u16 Bs[128 * 64];

    const int t = threadIdx.x;
    const int w = t >> 6, l = t & 63;
    const int wr = w >> 1, wc = w & 1;
    const int mBase = blockIdx.y * 128;
    const int nBase = blockIdx.x * 128;
    const int proj = nBase >> 10;            // block never straddles a proj
    const int nIn = nBase & (Ec - 1);
    const int lr = l >> 3, ls = l & 7;
    const int lq = l >> 4, ln = l & 15;

    f32x4 acc[4][4];
    #pragma unroll
    for (int i = 0; i < 4; ++i)
        #pragma unroll
        for (int j = 0; j < 4; ++j) acc[i][j] = (f32x4)0.f;

    for (int k0 = 0; k0 < Ec; k0 += 64) {
        __syncthreads();
        #pragma unroll
        for (int c = 0; c < 8; ++c) {
            int cg = w * 8 + c;
            if (cg < 16) {                   // A rows
                int row = cg * 8 + lr;
                int g = ls ^ (row & 7);
                gl_lds16(xb + ((size_t)(mBase + row)) * Ec + k0 + g * 8,
                         (void*)(As + cg * 512));
            } else {                         // B cols (Wtb rows)
                int col = (cg - 16) * 8 + lr;
                int g = ls ^ (col & 7);
                gl_lds16(Wtb + ((size_t)proj * Ec + nIn + col) * Ec + k0 + g * 8,
                         (void*)(Bs + (cg - 16) * 512));
            }
        }
        __syncthreads();

        #pragma unroll
        for (int ks = 0; ks < 2; ++ks) {
            short8 af[4], bfr[4];
            int gg = ks * 4 + lq;
            #pragma unroll
            for (int fm = 0; fm < 4; ++fm) {
                int row = wr * 64 + fm * 16 + ln;
                af[fm] = *(const short8*)(As + row * 64 + ((gg ^ (row & 7)) * 8));
            }
            #pragma unroll
            for (int fn = 0; fn < 4; ++fn) {
                int col = wc * 64 + fn * 16 + ln;
                bfr[fn] = *(const short8*)(Bs + col * 64 + ((gg ^ (col & 7)) * 8));
            }
            #pragma unroll
            for (int fm = 0; fm < 4; ++fm)
                #pragma unroll
                for (int fn = 0; fn < 4; ++fn)
                    acc[fm][fn] = __builtin_amdgcn_mfma_f32_16x16x32_bf16(
                        af[fm], bfr[fn], acc[fm][fn], 0, 0, 0);
        }
    }

    const float* bias = (proj == 0) ? bq : (proj == 1) ? bk : bv;
    #pragma unroll
    for (int fn = 0; fn < 4; ++fn) {
        int n = nBase + wc * 64 + fn * 16 + ln;
        int cc = n & (Ec - 1);
        int hh = cc >> 6, d = cc & 63;
        float bv_ = bias[cc];
        #pragma unroll
        for (int fm = 0; fm < 4; ++fm) {
            #pragma unroll
            for (int r = 0; r < 4; ++r) {
                int m = mBase + wr * 64 + fm * 16 + lq * 4 + r;
                int b = m >> 11, s = m & (Sc - 1);
                int bh = b * Hc + hh;
                float vv = acc[fm][fn][r] + bv_;
                // Q scaled by log2(e)/8 -> softmax in exp2 domain
                if (proj == 0)      qb[((size_t)bh * Sc + s) * DHc + d] = f2bf(vv * 0.18033688011f);
                else if (proj == 1) kb[((size_t)bh * Sc + s) * DHc + d] = f2bf(vv);
                else                vb[((size_t)bh * DHc + d) * Sc + s] = f2bf(vv);
            }
        }
    }
}

// ---------------------------------------------------------------------------
// Flash attention, bf16 MFMA, swapped-QK^T softmax, double-buffered K/V.
// Block = 256 q-rows x (h, b); 8 waves, 32 q-rows each. Grid = 512 blocks =
// exactly 2 resident blocks/CU (64 KB LDS, <=128 VGPR) -> no dispatch tail,
// 4 waves/SIMD to cover the softmax serial chain.
// Stage(kt+1) issued FIRST in iteration kt; one vmcnt+barrier per tile.
// ---------------------------------------------------------------------------
__global__ __launch_bounds__(512, 4)
void attn_mfma_kernel(const u16* __restrict__ qb, const u16* __restrict__ kb,
                      const u16* __restrict__ vb, u16* __restrict__ concatb)
{
    __shared__ __align__(16) u16 Kt[2][64 * 64];     // 16 KB
    __shared__ __align__(16) u16 Vt[2][64 * 64];     // 16 KB
    __shared__ __align__(16) u16 Ps[8 * 32 * 64];    // 32 KB: per-wave [32 q][64 key]

    const int t = threadIdx.x;
    const int w = t >> 6, l = t & 63;
    const int qt = blockIdx.x, h = blockIdx.y, b = blockIdx.z;
    const int bh = b * Hc + h;
    const int lq = l >> 4, ln = l & 15;
    const int lr = l >> 3, ls = l & 7;
    const int sw = ln & 7;

    const u16* qp = qb + ((size_t)bh * Sc + qt * 256 + w * 32) * DHc;
    const u16* kp = kb + (size_t)bh * Sc * DHc;
    const u16* vp = vb + (size_t)bh * DHc * Sc;
    u16* pw = Ps + w * (32 * 64);

    // per-wave staging: 2 chunks of (8 rows x 128B) per tile
    const int cg = w * 2;   // this wave's first chunk id (0..15)

    // Q fragments (B-operand): col=q=ln (within q-group), k=d=lq*8 + ks*32
    short8 qf[2][2];
    #pragma unroll
    for (int qg = 0; qg < 2; ++qg)
        #pragma unroll
        for (int ks = 0; ks < 2; ++ks)
            qf[qg][ks] = *(const short8*)(qp + (qg * 16 + ln) * DHc + ks * 32 + lq * 8);

    f32x4 o[2][4];
    #pragma unroll
    for (int qg = 0; qg < 2; ++qg)
        #pragma unroll
        for (int fd = 0; fd < 4; ++fd) o[qg][fd] = (f32x4)0.f;
    float m_i[2] = {-1e30f, -1e30f}, l_i[2] = {0.f, 0.f};

    // ---- prologue: stage tile 0 into buffer 0
    #pragma unroll
    for (int c = 0; c < 2; ++c) {
        int g2 = cg + c;
        if (g2 < 8) {
            int row = g2 * 8 + lr;
            int g = ls ^ (row & 7);
            gl_lds16(kp + ((size_t)row) * DHc + g * 8, (void*)(Kt[0] + g2 * 512));
        } else {
            int d = (g2 - 8) * 8 + lr;
            int g = ls ^ (d & 7);
            gl_lds16(vp + (size_t)d * Sc + g * 8, (void*)(Vt[0] + (g2 - 8) * 512));
        }
    }
    asm volatile("s_waitcnt vmcnt(0)" ::: "memory");
    __syncthreads();

    for (int kt = 0; kt < Sc / 64; ++kt) {
        const int cur = kt & 1;
        // ---- prefetch next tile into the other buffer (latency hides under compute)
        if (kt + 1 < Sc / 64) {
            const int nxt = cur ^ 1;
            #pragma unroll
            for (int c = 0; c < 2; ++c) {
                int g2 = cg + c;
                if (g2 < 8) {
                    int row = g2 * 8 + lr;
                    int g = ls ^ (row & 7);
                    gl_lds16(kp + ((size_t)((kt + 1) * 64 + row)) * DHc + g * 8,
                             (void*)(Kt[nxt] + g2 * 512));
                } else {
                    int d = (g2 - 8) * 8 + lr;
                    int g = ls ^ (d & 7);
                    gl_lds16(vp + (size_t)d * Sc + (kt + 1) * 64 + g * 8,
                             (void*)(Vt[nxt] + (g2 - 8) * 512));
                }
            }
        }

        // ---- S^T = K Q^T : D[key][q], lane: q=ln, key = fn*16 + lq*4 + r
        f32x4 s[2][4];
        #pragma unroll
        for (int qg = 0; qg < 2; ++qg)
            #pragma unroll
            for (int fn = 0; fn < 4; ++fn) s[qg][fn] = (f32x4)0.f;
        __builtin_amdgcn_s_setprio(1);
        #pragma unroll
        for (int ks = 0; ks < 2; ++ks) {
            int gg = ks * 4 + lq;
            #pragma unroll
            for (int fn = 0; fn < 4; ++fn) {
                int key = fn * 16 + ln;
                short8 kf = *(const short8*)(Kt[cur] + key * 64 + ((gg ^ sw) * 8));
                s[0][fn] = __builtin_amdgcn_mfma_f32_16x16x32_bf16(kf, qf[0][ks], s[0][fn], 0, 0, 0);
                s[1][fn] = __builtin_amdgcn_mfma_f32_16x16x32_bf16(kf, qf[1][ks], s[1][fn], 0, 0, 0);
            }
        }
        __builtin_amdgcn_s_setprio(0);

        // ---- online softmax, log2 domain, per-lane over 16 in-reg keys
        float pmax[2];
        #pragma unroll
        for (int qg = 0; qg < 2; ++qg) {
            float m0 = fmaxf(fmaxf(s[qg][0][0], s[qg][0][1]), fmaxf(s[qg][0][2], s[qg][0][3]));
            float m1 = fmaxf(fmaxf(s[qg][1][0], s[qg][1][1]), fmaxf(s[qg][1][2], s[qg][1][3]));
            float m2 = fmaxf(fmaxf(s[qg][2][0], s[qg][2][1]), fmaxf(s[qg][2][2], s[qg][2][3]));
            float m3 = fmaxf(fmaxf(s[qg][3][0], s[qg][3][1]), fmaxf(s[qg][3][2], s[qg][3][3]));
            float mx = fmaxf(fmaxf(m0, m1), fmaxf(m2, m3));
            mx = fmaxf(mx, __shfl_xor(mx, 16));
            mx = fmaxf(mx, __shfl_xor(mx, 32));
            pmax[qg] = mx;
        }
        bool need = (pmax[0] > m_i[0] + 8.f) || (pmax[1] > m_i[1] + 8.f);
        if (__any(need)) {                   // rare: rescale O, update m
            #pragma unroll
            for (int qg = 0; qg < 2; ++qg) {
                float nm = fmaxf(m_i[qg], pmax[qg]);
                float ef = exp2f(m_i[qg] - nm);
                l_i[qg] *= ef;
                m_i[qg] = nm;
                #pragma unroll
                for (int r = 0; r < 4; ++r) {
                    float efr = __shfl(ef, lq * 4 + r);   // ef of row q=lq*4+r
                    #pragma unroll
                    for (int fd = 0; fd < 4; ++fd) o[qg][fd][r] *= efr;
                }
            }
        }
        #pragma unroll
        for (int qg = 0; qg < 2; ++qg) {
            float p[4][4];
            float sum = 0.f;
            #pragma unroll
            for (int fn = 0; fn < 4; ++fn)
                #pragma unroll
                for (int r = 0; r < 4; ++r) {
                    p[fn][r] = exp2f(s[qg][fn][r] - m_i[qg]);
                    sum += p[fn][r];
                }
            sum += __shfl_xor(sum, 16);
            sum += __shfl_xor(sum, 32);
            l_i[qg] += sum;
            // pack pairs, write P[q][key] (b64, 16B-slot swizzled by q&7)
            #pragma unroll
            for (int fn = 0; fn < 4; ++fn) {
                unsigned int pa, pb;
                asm("v_cvt_pk_bf16_f32 %0, %1, %2" : "=v"(pa) : "v"(p[fn][0]), "v"(p[fn][1]));
                asm("v_cvt_pk_bf16_f32 %0, %1, %2" : "=v"(pb) : "v"(p[fn][2]), "v"(p[fn][3]));
                uint2 u; u.x = pa; u.y = pb;
                *(uint2*)(pw + (qg * 16 + ln) * 64 +
                          (((2 * fn + (lq >> 1)) ^ sw) << 3) + (lq & 1) * 4) = u;
            }
        }
        asm volatile("s_waitcnt lgkmcnt(0)" ::: "memory");

        // ---- O += P V : A = P[q][key] (reread), B = V[key][d] via Vt[d][key]
        __builtin_amdgcn_s_setprio(1);
        #pragma unroll
        for (int c = 0; c < 2; ++c) {
            int gg = c * 4 + lq;
            short8 pf0 = *(const short8*)(pw + ln * 64 + ((gg ^ sw) << 3));
            short8 pf1 = *(const short8*)(pw + (16 + ln) * 64 + ((gg ^ sw) << 3));
            #pragma unroll
            for (int fd = 0; fd < 4; ++fd) {
                int d = fd * 16 + ln;
                short8 vf = *(const short8*)(Vt[cur] + d * 64 + ((gg ^ sw) << 3));
                o[0][fd] = __builtin_amdgcn_mfma_f32_16x16x32_bf16(pf0, vf, o[0][fd], 0, 0, 0);
                o[1][fd] = __builtin_amdgcn_mfma_f32_16x16x32_bf16(pf1, vf, o[1][fd], 0, 0, 0);
            }
        }
        __builtin_amdgcn_s_setprio(0);

        // ---- next tile's loads complete; all waves done reading cur buffers
        asm volatile("s_waitcnt vmcnt(0)" ::: "memory");
        __syncthreads();
    }

    // ---- epilogue: normalize by row-l (pulled via shfl), write concat bf16
    #pragma unroll
    for (int qg = 0; qg < 2; ++qg) {
        #pragma unroll
        for (int r = 0; r < 4; ++r) {
            float lr_ = __shfl(l_i[qg], lq * 4 + r);
            float inv = 1.f / lr_;
            int q = qt * 256 + w * 32 + qg * 16 + lq * 4 + r;
            #pragma unroll
            for (int fd = 0; fd < 4; ++fd) {
                int d = h * DHc + fd * 16 + ln;
                concatb[((size_t)b * Sc + q) * Ec + d] = f2bf(o[qg][fd][r] * inv);
            }
        }
    }
}

// ---------------------------------------------------------------------------
// Output projection GEMM (bf16 MFMA): out[m][n] = concat[m][:] . Wo[n][:] + bo
// ---------------------------------------------------------------------------
__global__ __launch_bounds__(256)
void oproj_mfma_kernel(const u16* __restrict__ cb, const u16* __restrict__ Wob,
                       const float* __restrict__ bo, float* __restrict__ out)
{
    __shared__ __align__(16) u16 As[128 * 64];
    __shared__ __align__(16) u16 Bs[128 * 64];

    const int t = threadIdx.x;
    const int w = t >> 6, l = t & 63;
    const int wr = w >> 1, wc = w & 1;
    const int mBase = blockIdx.y * 128;
    const int nBase = blockIdx.x * 128;
    const int lr = l >> 3, ls = l & 7;
    const int lq = l >> 4, ln = l & 15;

    f32x4 acc[4][4];
    #pragma unroll
    for (int i = 0; i < 4; ++i)
        #pragma unroll
        for (int j = 0; j < 4; ++j) acc[i][j] = (f32x4)0.f;

    for (int k0 = 0; k0 < Ec; k0 += 64) {
        __syncthreads();
        #pragma unroll
        for (int c = 0; c < 8; ++c) {
            int cg = w * 8 + c;
            if (cg < 16) {
                int row = cg * 8 + lr;
                int g = ls ^ (row & 7);
                gl_lds16(cb + ((size_t)(mBase + row)) * Ec + k0 + g * 8,
                         (void*)(As + cg * 512));
            } else {
                int col = (cg - 16) * 8 + lr;
                int g = ls ^ (col & 7);
                gl_lds16(Wob + ((size_t)(nBase + col)) * Ec + k0 + g * 8,
                         (void*)(Bs + (cg - 16) * 512));
            }
        }
        __syncthreads();

        #pragma unroll
        for (int ks = 0; ks < 2; ++ks) {
            short8 af[4], bfr[4];
            int gg = ks * 4 + lq;
            #pragma unroll
            for (int fm = 0; fm < 4; ++fm) {
                int row = wr * 64 + fm * 16 + ln;
                af[fm] = *(const short8*)(As + row * 64 + ((gg ^ (row & 7)) * 8));
            }
            #pragma unroll
            for (int fn = 0; fn < 4; ++fn) {
                int col = wc * 64 + fn * 16 + ln;
                bfr[fn] = *(const short8*)(Bs + col * 64 + ((gg ^ (col & 7)) * 8));
            }
            #pragma unroll
            for (int fm = 0; fm < 4; ++fm)
                #pragma unroll
                for (int fn = 0; fn < 4; ++fn)
                    acc[fm][fn] = __builtin_amdgcn_mfma_f32_16x16x32_bf16(
                        af[fm], bfr[fn], acc[fm][fn], 0, 0, 0);
        }
    }

    #pragma unroll
    for (int fn = 0; fn < 4; ++fn) {
        int n = nBase + wc * 64 + fn * 16 + ln;
        float bb = bo[n];
        #pragma unroll
        for (int fm = 0; fm < 4; ++fm) {
            #pragma unroll
            for (int r = 0; r < 4; ++r) {
                int m = mBase + wr * 64 + fm * 16 + lq * 4 + r;
                out[(size_t)m * Ec + n] = acc[fm][fn][r] + bb;
            }
        }
    }
}

// ---------------------------------------------------------------------------
extern "C" void kernel_launch(void* const* d_in, const int* in_sizes, int n_in,
                              void* d_out, int out_size, void* d_ws, size_t ws_size,
                              hipStream_t stream)
{
    const float* x  = (const float*)d_in[0];
    const float* Wq = (const float*)d_in[1];
    const float* bq = (const float*)d_in[2];
    const float* Wk = (const float*)d_in[3];
    const float* bk = (const float*)d_in[4];
    const float* Wv = (const float*)d_in[5];
    const float* bv = (const float*)d_in[6];
    const float* Wo = (const float*)d_in[7];
    const float* bo = (const float*)d_in[8];
    float* out = (float*)d_out;

    char* ws = (char*)d_ws;
    u16* xb   = (u16*)(ws);                   // 16 MB  [8192][1024]
    u16* Wtb  = (u16*)(ws + (16u << 20));     //  6 MB  [3*1024][1024]
    u16* Wob  = (u16*)(ws + (22u << 20));     //  2 MB  [1024][1024]
    u16* qbuf = (u16*)(ws + (24u << 20));     // 16 MB  [bh][s][d], pre-scaled log2e/8
    u16* kbuf = (u16*)(ws + (40u << 20));     // 16 MB  [bh][s][d]
    u16* vbuf = (u16*)(ws + (56u << 20));     // 16 MB  [bh][d][s]  (transposed)
    u16* cbuf = (u16*)(ws + (72u << 20));     // 16 MB  [b][s][e]

    cast_bf16_kernel<<<(Bc * Sc * Ec / 8 + 255) / 256, 256, 0, stream>>>(x, xb, Bc * Sc * Ec / 8);
    cast_bf16_kernel<<<(Ec * Ec / 8 + 255) / 256, 256, 0, stream>>>(Wo, Wob, Ec * Ec / 8);
    dim3 gt(Ec / 64, Hc, 3);
    transW_kernel<<<gt, 256, 0, stream>>>(Wq, Wk, Wv, Wtb);

    dim3 g1(3 * Ec / 128, (Bc * Sc) / 128);   // (24, 64)
    qkv_mfma_kernel<<<g1, 256, 0, stream>>>(xb, Wtb, bq, bk, bv, qbuf, kbuf, vbuf);

    dim3 g2(Sc / 256, Hc, Bc);                // (8, 16, 4) = 512 blocks, 2/CU resident
    attn_mfma_kernel<<<g2, 512, 0, stream>>>(qbuf, kbuf, vbuf, cbuf);

    dim3 g3(Ec / 128, (Bc * Sc) / 128);       // (8, 64)
    oproj_mfma_kernel<<<g3, 256, 0, stream>>>(cbuf, Wob, bo, out);
}

// Round 7
// 244.450 us; speedup vs baseline: 9.0640x; 1.0750x over previous
//
#include <hip/hip_runtime.h>
#include <math.h>

#define Bc 4
#define Sc 2048
#define Ec 1024
#define Hc 16
#define DHc 64

typedef unsigned short u16;
typedef __attribute__((ext_vector_type(8))) short short8;   // 8 bf16 = 4 VGPR
typedef __attribute__((ext_vector_type(4))) float f32x4;
typedef __attribute__((ext_vector_type(16))) float f32x16;
typedef __attribute__((ext_vector_type(2))) unsigned short u16x2;

union pk8 { unsigned int u[4]; short8 v; };

__device__ __forceinline__ u16 f2bf(float f) {
    unsigned int u = __float_as_uint(f);
    u += 0x7FFFu + ((u >> 16) & 1u);          // round-to-nearest-even
    return (u16)(u >> 16);
}

// global -> LDS direct copy, 16B per lane. LDS dest is wave-uniform base
// (+ lane*16 implicit); global src is per-lane.
__device__ __forceinline__ void gl_lds16(const void* g, void* l) {
    __builtin_amdgcn_global_load_lds(
        (const __attribute__((address_space(1))) unsigned int*)g,
        (__attribute__((address_space(3))) unsigned int*)l,
        16, 0, 0);
}

// ---------------------------------------------------------------------------
// cast fp32 -> bf16, 8 elems/thread
// ---------------------------------------------------------------------------
__global__ __launch_bounds__(256)
void cast_bf16_kernel(const float* __restrict__ in, u16* __restrict__ out, int n8)
{
    int i = blockIdx.x * 256 + threadIdx.x;
    if (i >= n8) return;
    const float* p = in + (size_t)i * 8;
    float4 a = *(const float4*)p;
    float4 b = *(const float4*)(p + 4);
    short8 v;
    v[0] = (short)f2bf(a.x); v[1] = (short)f2bf(a.y);
    v[2] = (short)f2bf(a.z); v[3] = (short)f2bf(a.w);
    v[4] = (short)f2bf(b.x); v[5] = (short)f2bf(b.y);
    v[6] = (short)f2bf(b.z); v[7] = (short)f2bf(b.w);
    *(short8*)(out + (size_t)i * 8) = v;
}

// ---------------------------------------------------------------------------
// transpose+cast W[proj][h][e][d] fp32 -> Wtb[(proj*16+h)*64+d][e] bf16
// ---------------------------------------------------------------------------
__global__ __launch_bounds__(256)
void transW_kernel(const float* __restrict__ Wq, const float* __restrict__ Wk,
                   const float* __restrict__ Wv, u16* __restrict__ Wtb)
{
    __shared__ float T[64][65];
    const int t = threadIdx.x;
    const int e0 = blockIdx.x * 64;
    const int h = blockIdx.y;
    const int proj = blockIdx.z;
    const float* W = (proj == 0) ? Wq : (proj == 1) ? Wk : Wv;

    #pragma unroll
    for (int i = 0; i < 4; ++i) {
        int fid = t + i * 256;
        int row = fid >> 4, c4 = fid & 15;
        float4 v = *(const float4*)(W + ((size_t)h * Ec + e0 + row) * DHc + c4 * 4);
        T[row][c4 * 4 + 0] = v.x; T[row][c4 * 4 + 1] = v.y;
        T[row][c4 * 4 + 2] = v.z; T[row][c4 * 4 + 3] = v.w;
    }
    __syncthreads();
    const int d = t >> 2, ech = (t & 3) * 16;
    u16* dst = Wtb + ((size_t)(proj * Hc + h) * DHc + d) * Ec + e0 + ech;
    #pragma unroll
    for (int j = 0; j < 16; j += 2) {
        u16x2 v2;
        v2.x = f2bf(T[ech + j][d]);
        v2.y = f2bf(T[ech + j + 1][d]);
        *(u16x2*)(dst + j) = v2;
    }
}

// ---------------------------------------------------------------------------
// QKV projection GEMM (bf16 MFMA): M=8192, N=3072, K=1024.
// Q output pre-scaled by log2(e)/sqrt(DH) so attn softmax runs in exp2 domain.
// ---------------------------------------------------------------------------
__global__ __launch_bounds__(256)
void qkv_mfma_kernel(const u16* __restrict__ xb, const u16* __restrict__ Wtb,
                     const float* __restrict__ bq, const float* __restrict__ bk,
                     const float* __restrict__ bv,
                     u16* __restrict__ qb, u16* __restrict__ kb, u16* __restrict__ vb)
{
    __shared__ __align__(16) u16 As[128 * 64];
    __shared__ __align__(16) u16 Bs[128 * 64];

    const int t = threadIdx.x;
    const int w = t >> 6, l = t & 63;
    const int wr = w >> 1, wc = w & 1;
    const int mBase = blockIdx.y * 128;
    const int nBase = blockIdx.x * 128;
    const int proj = nBase >> 10;            // block never straddles a proj
    const int nIn = nBase & (Ec - 1);
    const int lr = l >> 3, ls = l & 7;
    const int lq = l >> 4, ln = l & 15;

    f32x4 acc[4][4];
    #pragma unroll
    for (int i = 0; i < 4; ++i)
        #pragma unroll
        for (int j = 0; j < 4; ++j) acc[i][j] = (f32x4)0.f;

    for (int k0 = 0; k0 < Ec; k0 += 64) {
        __syncthreads();
        #pragma unroll
        for (int c = 0; c < 8; ++c) {
            int cg = w * 8 + c;
            if (cg < 16) {                   // A rows
                int row = cg * 8 + lr;
                int g = ls ^ (row & 7);
                gl_lds16(xb + ((size_t)(mBase + row)) * Ec + k0 + g * 8,
                         (void*)(As + cg * 512));
            } else {                         // B cols (Wtb rows)
                int col = (cg - 16) * 8 + lr;
                int g = ls ^ (col & 7);
                gl_lds16(Wtb + ((size_t)proj * Ec + nIn + col) * Ec + k0 + g * 8,
                         (void*)(Bs + (cg - 16) * 512));
            }
        }
        __syncthreads();

        #pragma unroll
        for (int ks = 0; ks < 2; ++ks) {
            short8 af[4], bfr[4];
            int gg = ks * 4 + lq;
            #pragma unroll
            for (int fm = 0; fm < 4; ++fm) {
                int row = wr * 64 + fm * 16 + ln;
                af[fm] = *(const short8*)(As + row * 64 + ((gg ^ (row & 7)) * 8));
            }
            #pragma unroll
            for (int fn = 0; fn < 4; ++fn) {
                int col = wc * 64 + fn * 16 + ln;
                bfr[fn] = *(const short8*)(Bs + col * 64 + ((gg ^ (col & 7)) * 8));
            }
            #pragma unroll
            for (int fm = 0; fm < 4; ++fm)
                #pragma unroll
                for (int fn = 0; fn < 4; ++fn)
                    acc[fm][fn] = __builtin_amdgcn_mfma_f32_16x16x32_bf16(
                        af[fm], bfr[fn], acc[fm][fn], 0, 0, 0);
        }
    }

    const float* bias = (proj == 0) ? bq : (proj == 1) ? bk : bv;
    #pragma unroll
    for (int fn = 0; fn < 4; ++fn) {
        int n = nBase + wc * 64 + fn * 16 + ln;
        int cc = n & (Ec - 1);
        int hh = cc >> 6, d = cc & 63;
        float bv_ = bias[cc];
        #pragma unroll
        for (int fm = 0; fm < 4; ++fm) {
            #pragma unroll
            for (int r = 0; r < 4; ++r) {
                int m = mBase + wr * 64 + fm * 16 + lq * 4 + r;
                int b = m >> 11, s = m & (Sc - 1);
                int bh = b * Hc + hh;
                float vv = acc[fm][fn][r] + bv_;
                // Q scaled by log2(e)/8 -> softmax in exp2 domain
                if (proj == 0)      qb[((size_t)bh * Sc + s) * DHc + d] = f2bf(vv * 0.18033688011f);
                else if (proj == 1) kb[((size_t)bh * Sc + s) * DHc + d] = f2bf(vv);
                else                vb[((size_t)bh * DHc + d) * Sc + s] = f2bf(vv);
            }
        }
    }
}

// ---------------------------------------------------------------------------
// Flash attention, 32x32x16 bf16 MFMA, swapped-QK^T, fully in-register P.
// Block = 256 q-rows x (h, b); 8 waves, 32 q-rows each. Grid = 512 blocks.
// S^T = mfma(K, Q): lane (hi, q=l&31) holds 16 keys/kg in regs. Softmax is
// 31 in-lane ops + ONE shfl_xor(32) per reduction. P -> PV A-operand via
// cvt_pk + 4 cross-half shuffles + cndmask (no LDS round trip, no lgkm drain).
// K/V double-buffered in LDS (32 KB total), prefetch-first schedule.
// ---------------------------------------------------------------------------
__global__ __launch_bounds__(512, 4)
void attn_mfma_kernel(const u16* __restrict__ qb, const u16* __restrict__ kb,
                      const u16* __restrict__ vb, u16* __restrict__ concatb)
{
    __shared__ __align__(16) u16 Kt[2][64 * 64];     // [key][d], 16B-slot swz ^(key&7)
    __shared__ __align__(16) u16 Vt[2][64 * 64];     // [d][key], 16B-slot swz ^(d&7)

    const int t = threadIdx.x;
    const int w = t >> 6, l = t & 63;
    const int qt = blockIdx.x, h = blockIdx.y, b = blockIdx.z;
    const int bh = b * Hc + h;
    const int hi = l >> 5, l5 = l & 31;
    const int lr = l >> 3, ls = l & 7;               // staging lane split
    const int sw5 = l5 & 7;

    const u16* qp = qb + ((size_t)bh * Sc + qt * 256 + w * 32 + l5) * DHc;
    const u16* kp = kb + (size_t)bh * Sc * DHc;
    const u16* vp = vb + (size_t)bh * DHc * Sc;

    const int cg = w * 2;    // this wave's first staging chunk (0..15)

    // Q fragments (B-operand): lane (hi,q=l5) holds Q[q][d = ks*16 + hi*8 + j]
    short8 qf[4];
    #pragma unroll
    for (int ks = 0; ks < 4; ++ks)
        qf[ks] = *(const short8*)(qp + ks * 16 + hi * 8);

    f32x16 o0 = (f32x16)0.f, o1 = (f32x16)0.f;       // O[q rows][d = dg*32 + l5]
    float m_i = -1e30f, l_i = 0.f;                   // per q = l5 (dup across hi)

    // ---- prologue: stage tile 0 into buffer 0
    #pragma unroll
    for (int c = 0; c < 2; ++c) {
        int g2 = cg + c;
        if (g2 < 8) {
            int row = g2 * 8 + lr;
            int g = ls ^ (row & 7);
            gl_lds16(kp + ((size_t)row) * DHc + g * 8, (void*)(Kt[0] + g2 * 512));
        } else {
            int d = (g2 - 8) * 8 + lr;
            int g = ls ^ (d & 7);
            gl_lds16(vp + (size_t)d * Sc + g * 8, (void*)(Vt[0] + (g2 - 8) * 512));
        }
    }
    asm volatile("s_waitcnt vmcnt(0)" ::: "memory");
    __syncthreads();

    for (int kt = 0; kt < Sc / 64; ++kt) {
        const int cur = kt & 1;
        // ---- prefetch next tile into the other buffer
        if (kt + 1 < Sc / 64) {
            const int nxt = cur ^ 1;
            #pragma unroll
            for (int c = 0; c < 2; ++c) {
                int g2 = cg + c;
                if (g2 < 8) {
                    int row = g2 * 8 + lr;
                    int g = ls ^ (row & 7);
                    gl_lds16(kp + ((size_t)((kt + 1) * 64 + row)) * DHc + g * 8,
                             (void*)(Kt[nxt] + g2 * 512));
                } else {
                    int d = (g2 - 8) * 8 + lr;
                    int g = ls ^ (d & 7);
                    gl_lds16(vp + (size_t)d * Sc + (kt + 1) * 64 + g * 8,
                             (void*)(Vt[nxt] + (g2 - 8) * 512));
                }
            }
        }

        // ---- S^T = K Q^T : D[key][q=l5]; s0 = keys 0-31, s1 = keys 32-63
        f32x16 s0 = (f32x16)0.f, s1 = (f32x16)0.f;
        __builtin_amdgcn_s_setprio(1);
        #pragma unroll
        for (int ks = 0; ks < 4; ++ks) {
            int slot = ((2 * ks + hi) ^ sw5) * 8;
            short8 kf0 = *(const short8*)(Kt[cur] + (l5) * 64 + slot);
            short8 kf1 = *(const short8*)(Kt[cur] + (32 + l5) * 64 + slot);
            s0 = __builtin_amdgcn_mfma_f32_32x32x16_bf16(kf0, qf[ks], s0, 0, 0, 0);
            s1 = __builtin_amdgcn_mfma_f32_32x32x16_bf16(kf1, qf[ks], s1, 0, 0, 0);
        }
        __builtin_amdgcn_s_setprio(0);

        // ---- online softmax (log2 domain). Row q's 64 keys: 32 in-lane + 32 partner.
        float pm = fmaxf(s0[0], s0[1]);
        #pragma unroll
        for (int r = 2; r < 16; ++r) pm = fmaxf(pm, s0[r]);
        #pragma unroll
        for (int r = 0; r < 16; ++r) pm = fmaxf(pm, s1[r]);
        pm = fmaxf(pm, __shfl_xor(pm, 32));

        bool need = pm > m_i + 8.f;
        if (__any(need)) {                   // rare (tile 0 + outliers)
            float nm = fmaxf(m_i, pm);
            float ef = exp2f(m_i - nm);
            l_i *= ef;
            m_i = nm;
            #pragma unroll
            for (int r = 0; r < 16; ++r) {
                int qrow = (r & 3) + 8 * (r >> 2) + 4 * hi;
                float efq = __shfl(ef, qrow);
                o0[r] *= efq; o1[r] *= efq;
            }
        }

        float sum = 0.f;

        // ---- per key-group: exp -> pack -> cross-half exchange -> PV
#define PROC_KG(SV, KG)                                                         \
        {                                                                       \
            float p_[16];                                                       \
            _Pragma("unroll")                                                   \
            for (int r = 0; r < 16; ++r) {                                      \
                p_[r] = exp2f(SV[r] - m_i);                                     \
                sum += p_[r];                                                   \
            }                                                                   \
            unsigned int W_[8];                                                 \
            _Pragma("unroll")                                                   \
            for (int i = 0; i < 8; ++i)                                         \
                asm("v_cvt_pk_bf16_f32 %0, %1, %2"                              \
                    : "=v"(W_[i]) : "v"(p_[2 * i]), "v"(p_[2 * i + 1]));        \
            unsigned int r0 = __shfl_xor(hi ? W_[0] : W_[2], 32);               \
            unsigned int r1 = __shfl_xor(hi ? W_[1] : W_[3], 32);               \
            unsigned int r2 = __shfl_xor(hi ? W_[4] : W_[6], 32);               \
            unsigned int r3 = __shfl_xor(hi ? W_[5] : W_[7], 32);               \
            pk8 a0, a1;                                                         \
            a0.u[0] = hi ? r0 : W_[0];  a0.u[1] = hi ? r1 : W_[1];              \
            a0.u[2] = hi ? W_[2] : r0;  a0.u[3] = hi ? W_[3] : r1;              \
            a1.u[0] = hi ? r2 : W_[4];  a1.u[1] = hi ? r3 : W_[5];              \
            a1.u[2] = hi ? W_[6] : r2;  a1.u[3] = hi ? W_[7] : r3;              \
            _Pragma("unroll")                                                   \
            for (int ksl = 0; ksl < 2; ++ksl) {                                 \
                int slot = (((KG * 4 + ksl * 2 + hi)) ^ sw5) * 8;               \
                short8 vf0 = *(const short8*)(Vt[cur] + (l5) * 64 + slot);      \
                short8 vf1 = *(const short8*)(Vt[cur] + (32 + l5) * 64 + slot); \
                short8 pa = ksl ? a1.v : a0.v;                                  \
                o0 = __builtin_amdgcn_mfma_f32_32x32x16_bf16(pa, vf0, o0, 0, 0, 0); \
                o1 = __builtin_amdgcn_mfma_f32_32x32x16_bf16(pa, vf1, o1, 0, 0, 0); \
            }                                                                   \
        }

        __builtin_amdgcn_s_setprio(1);
        PROC_KG(s0, 0)
        PROC_KG(s1, 1)
        __builtin_amdgcn_s_setprio(0);
#undef PROC_KG

        sum += __shfl_xor(sum, 32);
        l_i += sum;

        // ---- next tile's loads complete; all waves done reading cur buffers
        asm volatile("s_waitcnt vmcnt(0)" ::: "memory");
        __syncthreads();
    }

    // ---- epilogue: normalize per q-row (l gathered via shfl), write concat
    #pragma unroll
    for (int r = 0; r < 16; ++r) {
        int qrow = (r & 3) + 8 * (r >> 2) + 4 * hi;
        float inv = 1.f / __shfl(l_i, qrow);
        int q = qt * 256 + w * 32 + qrow;
        u16* dst = concatb + ((size_t)b * Sc + q) * Ec + h * DHc + l5;
        dst[0]  = f2bf(o0[r] * inv);
        dst[32] = f2bf(o1[r] * inv);
    }
}

// ---------------------------------------------------------------------------
// Output projection GEMM (bf16 MFMA): out[m][n] = concat[m][:] . Wo[n][:] + bo
// ---------------------------------------------------------------------------
__global__ __launch_bounds__(256)
void oproj_mfma_kernel(const u16* __restrict__ cb, const u16* __restrict__ Wob,
                       const float* __restrict__ bo, float* __restrict__ out)
{
    __shared__ __align__(16) u16 As[128 * 64];
    __shared__ __align__(16) u16 Bs[128 * 64];

    const int t = threadIdx.x;
    const int w = t >> 6, l = t & 63;
    const int wr = w >> 1, wc = w & 1;
    const int mBase = blockIdx.y * 128;
    const int nBase = blockIdx.x * 128;
    const int lr = l >> 3, ls = l & 7;
    const int lq = l >> 4, ln = l & 15;

    f32x4 acc[4][4];
    #pragma unroll
    for (int i = 0; i < 4; ++i)
        #pragma unroll
        for (int j = 0; j < 4; ++j) acc[i][j] = (f32x4)0.f;

    for (int k0 = 0; k0 < Ec; k0 += 64) {
        __syncthreads();
        #pragma unroll
        for (int c = 0; c < 8; ++c) {
            int cg = w * 8 + c;
            if (cg < 16) {
                int row = cg * 8 + lr;
                int g = ls ^ (row & 7);
                gl_lds16(cb + ((size_t)(mBase + row)) * Ec + k0 + g * 8,
                         (void*)(As + cg * 512));
            } else {
                int col = (cg - 16) * 8 + lr;
                int g = ls ^ (col & 7);
                gl_lds16(Wob + ((size_t)(nBase + col)) * Ec + k0 + g * 8,
                         (void*)(Bs + (cg - 16) * 512));
            }
        }
        __syncthreads();

        #pragma unroll
        for (int ks = 0; ks < 2; ++ks) {
            short8 af[4], bfr[4];
            int gg = ks * 4 + lq;
            #pragma unroll
            for (int fm = 0; fm < 4; ++fm) {
                int row = wr * 64 + fm * 16 + ln;
                af[fm] = *(const short8*)(As + row * 64 + ((gg ^ (row & 7)) * 8));
            }
            #pragma unroll
            for (int fn = 0; fn < 4; ++fn) {
                int col = wc * 64 + fn * 16 + ln;
                bfr[fn] = *(const short8*)(Bs + col * 64 + ((gg ^ (col & 7)) * 8));
            }
            #pragma unroll
            for (int fm = 0; fm < 4; ++fm)
                #pragma unroll
                for (int fn = 0; fn < 4; ++fn)
                    acc[fm][fn] = __builtin_amdgcn_mfma_f32_16x16x32_bf16(
                        af[fm], bfr[fn], acc[fm][fn], 0, 0, 0);
        }
    }

    #pragma unroll
    for (int fn = 0; fn < 4; ++fn) {
        int n = nBase + wc * 64 + fn * 16 + ln;
        float bb = bo[n];
        #pragma unroll
        for (int fm = 0; fm < 4; ++fm) {
            #pragma unroll
            for (int r = 0; r < 4; ++r) {
                int m = mBase + wr * 64 + fm * 16 + lq * 4 + r;
                out[(size_t)m * Ec + n] = acc[fm][fn][r] + bb;
            }
        }
    }
}

// ---------------------------------------------------------------------------
extern "C" void kernel_launch(void* const* d_in, const int* in_sizes, int n_in,
                              void* d_out, int out_size, void* d_ws, size_t ws_size,
                              hipStream_t stream)
{
    const float* x  = (const float*)d_in[0];
    const float* Wq = (const float*)d_in[1];
    const float* bq = (const float*)d_in[2];
    const float* Wk = (const float*)d_in[3];
    const float* bk = (const float*)d_in[4];
    const float* Wv = (const float*)d_in[5];
    const float* bv = (const float*)d_in[6];
    const float* Wo = (const float*)d_in[7];
    const float* bo = (const float*)d_in[8];
    float* out = (float*)d_out;

    char* ws = (char*)d_ws;
    u16* xb   = (u16*)(ws);                   // 16 MB  [8192][1024]
    u16* Wtb  = (u16*)(ws + (16u << 20));     //  6 MB  [3*1024][1024]
    u16* Wob  = (u16*)(ws + (22u << 20));     //  2 MB  [1024][1024]
    u16* qbuf = (u16*)(ws + (24u << 20));     // 16 MB  [bh][s][d], pre-scaled log2e/8
    u16* kbuf = (u16*)(ws + (40u << 20));     // 16 MB  [bh][s][d]
    u16* vbuf = (u16*)(ws + (56u << 20));     // 16 MB  [bh][d][s]  (transposed)
    u16* cbuf = (u16*)(ws + (72u << 20));     // 16 MB  [b][s][e]

    cast_bf16_kernel<<<(Bc * Sc * Ec / 8 + 255) / 256, 256, 0, stream>>>(x, xb, Bc * Sc * Ec / 8);
    cast_bf16_kernel<<<(Ec * Ec / 8 + 255) / 256, 256, 0, stream>>>(Wo, Wob, Ec * Ec / 8);
    dim3 gt(Ec / 64, Hc, 3);
    transW_kernel<<<gt, 256, 0, stream>>>(Wq, Wk, Wv, Wtb);

    dim3 g1(3 * Ec / 128, (Bc * Sc) / 128);   // (24, 64)
    qkv_mfma_kernel<<<g1, 256, 0, stream>>>(xb, Wtb, bq, bk, bv, qbuf, kbuf, vbuf);

    dim3 g2(Sc / 256, Hc, Bc);                // (8, 16, 4) = 512 blocks, 2/CU resident
    attn_mfma_kernel<<<g2, 512, 0, stream>>>(qbuf, kbuf, vbuf, cbuf);

    dim3 g3(Ec / 128, (Bc * Sc) / 128);       // (8, 64)
    oproj_mfma_kernel<<<g3, 256, 0, stream>>>(cbuf, Wob, bo, out);
}